// Round 8
// baseline (353.537 us; speedup 1.0000x reference)
//
#include <hip/hip_runtime.h>

#define FEAT 128
#define BSH 7
#define BNODES 128            // nodes per bucket = 1<<BSH
#define ATILE 4096            // edges per binning block
#define MAXNB 1024            // bin path requires NB <= 1024
#define STILE 1024

typedef __attribute__((ext_vector_type(8))) short bf16x8;
typedef __attribute__((ext_vector_type(4))) float f32x4;

// ======================= tiny kernels =======================
__global__ void k_zero_i32(int* __restrict__ p, int n) {
    int i = blockIdx.x * blockDim.x + threadIdx.x;
    if (i < n) p[i] = 0;
}

__global__ void k_count(const int* __restrict__ dst, int* __restrict__ cnt, int E) {
    int i = blockIdx.x * blockDim.x + threadIdx.x;
    if (i < E) atomicAdd(&cnt[dst[i]], 1);
}

__global__ void k_dinv(const int* __restrict__ cnt, float* __restrict__ dinv, int N) {
    int i = blockIdx.x * blockDim.x + threadIdx.x;
    if (i < N) dinv[i] = rsqrtf((float)cnt[i] + 1.0f);
}

__global__ void k_bucket_base(const int* __restrict__ offs, int* __restrict__ cur, int NB) {
    int b = blockIdx.x * blockDim.x + threadIdx.x;
    if (b < NB) cur[b] = offs[b << BSH];
}

__device__ inline unsigned int f2bf(float f) {
    unsigned int u = __float_as_uint(f);
    return (u + 0x7FFFu + ((u >> 16) & 1u)) >> 16;   // RNE
}

// ======================= K1: combined {zero bCnt | cvt x->bf16 | cvt W} =======================
__global__ __launch_bounds__(256) void k_pre(const float* __restrict__ x,
                                             unsigned int* __restrict__ xbf,
                                             const float* __restrict__ W,
                                             unsigned short* __restrict__ wt,
                                             int* __restrict__ bCnt,
                                             long long n8, int NB,
                                             int zb, int cb, int wb) {
    int blk = blockIdx.x;
    if (blk < zb) {
        int i = blk * 256 + threadIdx.x;
        if (i < NB) bCnt[i] = 0;
        return;
    }
    blk -= zb;
    if (blk < cb) {
        long long i = (long long)blk * 256 + threadIdx.x;
        if (i >= n8) return;
        float4 a = ((const float4*)x)[i * 2];
        float4 c = ((const float4*)x)[i * 2 + 1];
        uint4 o;
        o.x = f2bf(a.x) | (f2bf(a.y) << 16);
        o.y = f2bf(a.z) | (f2bf(a.w) << 16);
        o.z = f2bf(c.x) | (f2bf(c.y) << 16);
        o.w = f2bf(c.z) | (f2bf(c.w) << 16);
        ((uint4*)xbf)[i] = o;
        return;
    }
    blk -= cb;
    if (blk < wb) {
        int i = blk * 256 + threadIdx.x;
        if (i >= FEAT * FEAT) return;
        int n = i >> 7, k = i & 127;
        wt[i] = (unsigned short)f2bf(W[k * FEAT + n]);
    }
}

// standalone cvt kernels (tier B)
__global__ void k_cvt_bf16(const float* __restrict__ x, unsigned int* __restrict__ xbf,
                           long long n8) {
    long long i = (long long)blockIdx.x * blockDim.x + threadIdx.x;
    if (i >= n8) return;
    float4 a = ((const float4*)x)[i * 2];
    float4 c = ((const float4*)x)[i * 2 + 1];
    uint4 o;
    o.x = f2bf(a.x) | (f2bf(a.y) << 16);
    o.y = f2bf(a.z) | (f2bf(a.w) << 16);
    o.z = f2bf(c.x) | (f2bf(c.y) << 16);
    o.w = f2bf(c.z) | (f2bf(c.w) << 16);
    ((uint4*)xbf)[i] = o;
}
__global__ void k_cvt_w(const float* __restrict__ W, unsigned short* __restrict__ wt) {
    int i = blockIdx.x * blockDim.x + threadIdx.x;
    if (i >= FEAT * FEAT) return;
    int n = i >> 7, k = i & 127;
    wt[i] = (unsigned short)f2bf(W[k * FEAT + n]);
}

// ======================= bucket-level hist + scan =======================
__global__ __launch_bounds__(256) void k_hist_bucket(const int* __restrict__ dst,
                                                     int* __restrict__ bCnt, int E, int NB) {
    __shared__ int h[MAXNB];
    int tid = threadIdx.x;
    for (int i = tid; i < NB; i += 256) h[i] = 0;
    __syncthreads();
    int base = blockIdx.x * ATILE;
    int end = min(base + ATILE, E);
    for (int e = base + tid; e < end; e += 256)
        atomicAdd(&h[dst[e] >> BSH], 1);
    __syncthreads();
    for (int i = tid; i < NB; i += 256)
        if (h[i]) atomicAdd(&bCnt[i], h[i]);
}

__global__ void k_scan_bucket(const int* __restrict__ bCnt, int* __restrict__ bOffs,
                              int* __restrict__ cur, int NB, int E) {
    __shared__ int s[256];
    int t = threadIdx.x;
    int carry = 0;
    for (int base = 0; base < NB; base += 256) {
        int i = base + t;
        int v = (i < NB) ? bCnt[i] : 0;
        s[t] = v; __syncthreads();
        for (int o = 1; o < 256; o <<= 1) {
            int add = (t >= o) ? s[t - o] : 0;
            __syncthreads();
            s[t] += add;
            __syncthreads();
        }
        if (i < NB) { int ex = s[t] - v + carry; bOffs[i] = ex; cur[i] = ex; }
        __syncthreads();
        carry += s[255];
        __syncthreads();
    }
    if (t == 0) bOffs[NB] = E;
}

// ======================= N-scan (tier B only) =======================
__global__ void k_scan_partial(const int* __restrict__ cnt, int* __restrict__ part, int N) {
    __shared__ int s[256];
    int base = blockIdx.x * STILE;
    int t = threadIdx.x;
    int sum = 0;
#pragma unroll
    for (int k = 0; k < 4; ++k) {
        int i = base + t * 4 + k;
        if (i < N) sum += cnt[i];
    }
    s[t] = sum; __syncthreads();
    for (int off = 128; off > 0; off >>= 1) {
        if (t < off) s[t] += s[t + off];
        __syncthreads();
    }
    if (t == 0) part[blockIdx.x] = s[0];
}

__global__ void k_scan_top(int* __restrict__ part, int nTiles) {
    __shared__ int s[256];
    int t = threadIdx.x;
    int carry = 0;
    for (int base = 0; base < nTiles; base += 256) {
        int i = base + t;
        int v = (i < nTiles) ? part[i] : 0;
        s[t] = v; __syncthreads();
        for (int o = 1; o < 256; o <<= 1) {
            int add = (t >= o) ? s[t - o] : 0;
            __syncthreads();
            s[t] += add;
            __syncthreads();
        }
        if (i < nTiles) part[i] = (s[t] - v) + carry;
        __syncthreads();
        carry += s[255];
        __syncthreads();
    }
}

__global__ void k_scan_final(const int* __restrict__ cnt, const int* __restrict__ part,
                             int* __restrict__ offs, int N) {
    __shared__ int s[256];
    int base = blockIdx.x * STILE;
    int t = threadIdx.x;
    int v[4]; int sum = 0;
#pragma unroll
    for (int k = 0; k < 4; ++k) {
        int i = base + t * 4 + k;
        v[k] = (i < N) ? cnt[i] : 0;
        sum += v[k];
    }
    s[t] = sum; __syncthreads();
    for (int o = 1; o < 256; o <<= 1) {
        int add = (t >= o) ? s[t - o] : 0;
        __syncthreads();
        s[t] += add;
        __syncthreads();
    }
    int excl = (s[t] - sum) + part[blockIdx.x];
#pragma unroll
    for (int k = 0; k < 4; ++k) {
        int i = base + t * 4 + k;
        if (i < N) offs[i] = excl;
        excl += v[k];
    }
}

// ======================= pass A: bin edges by dst bucket =======================
__global__ __launch_bounds__(256) void k_bin(const int* __restrict__ src,
                                             const int* __restrict__ dst,
                                             int* __restrict__ cur,
                                             unsigned int* __restrict__ pairs,
                                             int E, int NB) {
    __shared__ int hist[MAXNB];
    __shared__ int tbase[MAXNB];
    __shared__ int sc[256];
    __shared__ unsigned int stM[ATILE];
    __shared__ unsigned short stB[ATILE];

    int tid = threadIdx.x;
    int tileBase = blockIdx.x * ATILE;
    int tileCnt = min(ATILE, E - tileBase);

    for (int i = tid; i < NB; i += 256) hist[i] = 0;
    __syncthreads();

    unsigned int pk[16]; unsigned short bk[16]; unsigned short rk[16];
#pragma unroll
    for (int k = 0; k < 16; ++k) {
        int e = tileBase + k * 256 + tid;
        if (e < E) {
            int s = src[e], d = dst[e];
            int b = d >> BSH;
            int r = atomicAdd(&hist[b], 1);
            pk[k] = (unsigned int)s | ((unsigned int)(d & (BNODES - 1)) << 24);
            bk[k] = (unsigned short)b;
            rk[k] = (unsigned short)r;
        }
    }
    __syncthreads();

    int per = (NB + 255) / 256;
    int myBase = tid * per;
    int partial = 0;
    for (int i = 0; i < per; ++i) {
        int idx = myBase + i;
        if (idx < NB) partial += hist[idx];
    }
    sc[tid] = partial;
    __syncthreads();
    for (int o = 1; o < 256; o <<= 1) {
        int add = (tid >= o) ? sc[tid - o] : 0;
        __syncthreads();
        sc[tid] += add;
        __syncthreads();
    }
    int run = (tid == 0) ? 0 : sc[tid - 1];
    for (int i = 0; i < per; ++i) {
        int idx = myBase + i;
        if (idx < NB) {
            int c = hist[idx];
            hist[idx] = run;
            if (c > 0) {
                int g = atomicAdd(&cur[idx], c);
                tbase[idx] = g - run;
            }
            run += c;
        }
    }
    __syncthreads();

#pragma unroll
    for (int k = 0; k < 16; ++k) {
        int e = tileBase + k * 256 + tid;
        if (e < E) {
            int slot = hist[bk[k]] + (int)rk[k];
            stM[slot] = pk[k];
            stB[slot] = bk[k];
        }
    }
    __syncthreads();

    for (int s = tid; s < tileCnt; s += 256) {
        int gpos = tbase[stB[s]] + s;
        pairs[gpos] = stM[s];
    }
}

// ======================= pass B: per-bucket cnt/offs/dinv + CSR fill =======================
__global__ __launch_bounds__(256) void k_fill_local2(const unsigned int* __restrict__ pairs,
                                                     const int* __restrict__ bOffs,
                                                     unsigned int* __restrict__ csr,
                                                     int* __restrict__ g_cnt,
                                                     int* __restrict__ g_offs,
                                                     float* __restrict__ g_dinv,
                                                     int N) {
    __shared__ int lcnt[BNODES];
    __shared__ int lexcl[BNODES];
    __shared__ int lcur[BNODES];
    int b = blockIdx.x;
    int node0 = b << BSH;
    int nn = min(BNODES, N - node0);
    int tid = threadIdx.x;
    int bstart = bOffs[b], bend = bOffs[b + 1];

    if (tid < BNODES) lcnt[tid] = 0;
    __syncthreads();
    for (int i = bstart + tid; i < bend; i += 256)
        atomicAdd(&lcnt[pairs[i] >> 24], 1);
    __syncthreads();
    if (tid < BNODES) lexcl[tid] = lcnt[tid];
    __syncthreads();
    for (int o = 1; o < BNODES; o <<= 1) {
        int add = (tid < BNODES && tid >= o) ? lexcl[tid - o] : 0;
        __syncthreads();
        if (tid < BNODES) lexcl[tid] += add;
        __syncthreads();
    }
    if (tid < BNODES) {
        int ex = bstart + lexcl[tid] - lcnt[tid];
        lcur[tid] = ex;
        if (tid < nn) {
            g_cnt[node0 + tid] = lcnt[tid];
            g_offs[node0 + tid] = ex;
            g_dinv[node0 + tid] = rsqrtf((float)lcnt[tid] + 1.0f);
        }
    }
    __syncthreads();
    for (int i = bstart + tid; i < bend; i += 256) {
        unsigned int p = pairs[i];
        int dl = (int)(p >> 24);
        int pos = atomicAdd(&lcur[dl], 1);
        csr[pos] = p & 0xFFFFFFu;
    }
}

// ======================= K6: fused aggregate + MFMA GEMM (one bucket per block) =======================
// 8 waves; wave w aggregates nodes node0+w*16 .. +15 into its private LDS row slice (bf16),
// then runs its own 16x128 MFMA mtile from LDS. No inter-wave dependency -> no barrier.
#define RSTRIDE 68   // dwords per row (64 data + 4 pad): byte stride 272 (16B-aligned, bank-spread)
__global__ __launch_bounds__(512) void k_agg_gemm(const unsigned int* __restrict__ xbf,
                                                  const float* __restrict__ dinv,
                                                  const int* __restrict__ offs,
                                                  const int* __restrict__ cnt,
                                                  const unsigned int* __restrict__ csr,
                                                  const unsigned short* __restrict__ wt,
                                                  const float* __restrict__ bias,
                                                  float* __restrict__ out, int N) {
    __shared__ unsigned int rows[8 * 16 * RSTRIDE];   // 34816 B
    int tid = threadIdx.x;
    int wave = tid >> 6, lane = tid & 63;
    int nodeBase = (blockIdx.x << BSH) + wave * 16;
    unsigned int* my = rows + wave * 16 * RSTRIDE;

    if (nodeBase < N) {
        // ---- aggregate 16 nodes (wave-serial; node id uniform -> scalar csr/dinv path) ----
        int nlim = min(16, N - nodeBase);
        for (int i = 0; i < nlim; ++i) {
            int n = nodeBase + i;
            float di = dinv[n];
            int start = offs[n];
            int m = cnt[n];

            unsigned int wself = xbf[(size_t)n * 64 + lane];
            float sl = di * di;
            float2 acc = make_float2(sl * __uint_as_float(wself << 16),
                                     sl * __uint_as_float(wself & 0xFFFF0000u));

            int e = 0;
            for (; e + 8 <= m; e += 8) {
                int s[8]; float nr[8]; unsigned int w[8];
#pragma unroll
                for (int u = 0; u < 8; ++u) s[u] = (int)csr[start + e + u];
#pragma unroll
                for (int u = 0; u < 8; ++u) w[u] = xbf[(size_t)s[u] * 64 + lane];
#pragma unroll
                for (int u = 0; u < 8; ++u) nr[u] = dinv[s[u]] * di;
#pragma unroll
                for (int u = 0; u < 8; ++u) {
                    acc.x += nr[u] * __uint_as_float(w[u] << 16);
                    acc.y += nr[u] * __uint_as_float(w[u] & 0xFFFF0000u);
                }
            }
            for (; e < m; ++e) {
                int s0 = (int)csr[start + e];
                float n0 = dinv[s0] * di;
                unsigned int w0 = xbf[(size_t)s0 * 64 + lane];
                acc.x += n0 * __uint_as_float(w0 << 16);
                acc.y += n0 * __uint_as_float(w0 & 0xFFFF0000u);
            }
            my[i * RSTRIDE + lane] = f2bf(acc.x) | (f2bf(acc.y) << 16);
        }

        // ---- GEMM this wave's 16-row mtile: out[rows] = A(16x128) @ Wt^T + b ----
        int lm = lane & 15, lg = lane >> 4;
        f32x4 acc[8];
#pragma unroll
        for (int nt = 0; nt < 8; ++nt) acc[nt] = (f32x4){0.f, 0.f, 0.f, 0.f};

#pragma unroll
        for (int kk = 0; kk < 4; ++kk) {
            int k = kk * 32 + lg * 8;              // bf16 k-base
            bf16x8 afr = *(const bf16x8*)((const unsigned short*)(my + lm * RSTRIDE) + k);
#pragma unroll
            for (int nt = 0; nt < 8; ++nt) {
                int col = nt * 16 + lm;
                bf16x8 bfr = *(const bf16x8*)(wt + (size_t)col * FEAT + k);
                acc[nt] = __builtin_amdgcn_mfma_f32_16x16x32_bf16(afr, bfr, acc[nt], 0, 0, 0);
            }
        }

#pragma unroll
        for (int nt = 0; nt < 8; ++nt) {
            int col = nt * 16 + lm;
            float bv = bias[col];
#pragma unroll
            for (int r = 0; r < 4; ++r) {
                int row = nodeBase + lg * 4 + r;
                if (row < N) out[(size_t)row * FEAT + col] = acc[nt][r] + bv;
            }
        }
    }
}

// ======================= tier B kernels (R7 path) =======================
__global__ __launch_bounds__(256) void k_aggregate_bf2(const unsigned int* __restrict__ xbf,
                                                       const float* __restrict__ dinv,
                                                       const int* __restrict__ offs,
                                                       const int* __restrict__ cnt,
                                                       const unsigned int* __restrict__ csr,
                                                       unsigned int* __restrict__ aggbf,
                                                       int N) {
    int wid = (blockIdx.x * blockDim.x + threadIdx.x) >> 6;
    int lane = threadIdx.x & 63;
    if (wid >= N) return;
    int n = __builtin_amdgcn_readfirstlane(wid);

    float di = dinv[n];
    int start = offs[n];
    int m = cnt[n];

    unsigned int wself = xbf[(size_t)n * 64 + lane];
    float sl = di * di;
    float2 acc = make_float2(sl * __uint_as_float(wself << 16),
                             sl * __uint_as_float(wself & 0xFFFF0000u));

    int i = 0;
    for (; i + 8 <= m; i += 8) {
        int s[8]; float nr[8]; unsigned int w[8];
#pragma unroll
        for (int u = 0; u < 8; ++u) s[u] = (int)csr[start + i + u];
#pragma unroll
        for (int u = 0; u < 8; ++u) w[u] = xbf[(size_t)s[u] * 64 + lane];
#pragma unroll
        for (int u = 0; u < 8; ++u) nr[u] = dinv[s[u]] * di;
#pragma unroll
        for (int u = 0; u < 8; ++u) {
            acc.x += nr[u] * __uint_as_float(w[u] << 16);
            acc.y += nr[u] * __uint_as_float(w[u] & 0xFFFF0000u);
        }
    }
    for (; i < m; ++i) {
        int s0 = (int)csr[start + i];
        float n0 = dinv[s0] * di;
        unsigned int w0 = xbf[(size_t)s0 * 64 + lane];
        acc.x += n0 * __uint_as_float(w0 << 16);
        acc.y += n0 * __uint_as_float(w0 & 0xFFFF0000u);
    }
    aggbf[(size_t)n * 64 + lane] = f2bf(acc.x) | (f2bf(acc.y) << 16);
}

__global__ __launch_bounds__(256) void k_gemm_mfma2(const unsigned short* __restrict__ abf,
                                                    const unsigned short* __restrict__ wt,
                                                    const float* __restrict__ bias,
                                                    float* __restrict__ out, int N) {
    int tid = threadIdx.x;
    int wave = tid >> 6, l = tid & 63;
    int lm = l & 15, lg = l >> 4;
    int rowA = blockIdx.x * 128 + wave * 32;

    f32x4 acc[2][8];
#pragma unroll
    for (int mt = 0; mt < 2; ++mt)
#pragma unroll
        for (int nt = 0; nt < 8; ++nt)
            acc[mt][nt] = (f32x4){0.f, 0.f, 0.f, 0.f};

#pragma unroll
    for (int kk = 0; kk < 4; ++kk) {
        int k = kk * 32 + lg * 8;
        bf16x8 afr[2];
#pragma unroll
        for (int mt = 0; mt < 2; ++mt) {
            int r = rowA + mt * 16 + lm;
            if (r < N)
                afr[mt] = *(const bf16x8*)(abf + (size_t)r * FEAT + k);
            else
                afr[mt] = (bf16x8){0, 0, 0, 0, 0, 0, 0, 0};
        }
#pragma unroll
        for (int nt = 0; nt < 8; ++nt) {
            int col = nt * 16 + lm;
            bf16x8 bfr = *(const bf16x8*)(wt + (size_t)col * FEAT + k);
            acc[0][nt] = __builtin_amdgcn_mfma_f32_16x16x32_bf16(afr[0], bfr, acc[0][nt], 0, 0, 0);
            acc[1][nt] = __builtin_amdgcn_mfma_f32_16x16x32_bf16(afr[1], bfr, acc[1][nt], 0, 0, 0);
        }
    }

#pragma unroll
    for (int nt = 0; nt < 8; ++nt) {
        int col = nt * 16 + lm;
        float bv = bias[col];
#pragma unroll
        for (int mt = 0; mt < 2; ++mt) {
#pragma unroll
            for (int r = 0; r < 4; ++r) {
                int row = rowA + mt * 16 + lg * 4 + r;
                if (row < N) out[(size_t)row * FEAT + col] = acc[mt][nt][r] + bv;
            }
        }
    }
}

__global__ __launch_bounds__(256) void k_fill_local(const unsigned int* __restrict__ pairs,
                                                    const int* __restrict__ offs,
                                                    unsigned int* __restrict__ csr,
                                                    int N, int E) {
    __shared__ int lcur[BNODES];
    int b = blockIdx.x;
    int node0 = b << BSH;
    int nn = min(BNODES, N - node0);
    int tid = threadIdx.x;
    for (int i = tid; i < nn; i += 256) lcur[i] = offs[node0 + i];
    __syncthreads();
    int start = offs[node0];
    int end = (node0 + BNODES >= N) ? E : offs[node0 + BNODES];
    for (int i = start + tid; i < end; i += 256) {
        unsigned int p = pairs[i];
        int dl = (int)(p >> 24);
        int pos = atomicAdd(&lcur[dl], 1);
        csr[pos] = p & 0xFFFFFFu;
    }
}

__global__ __launch_bounds__(256) void k_aggregate(const float* __restrict__ x,
                                                   const float* __restrict__ dinv,
                                                   const int* __restrict__ offs,
                                                   const int* __restrict__ cnt,
                                                   const unsigned int* __restrict__ csr,
                                                   float* __restrict__ out, int N) {
    int wid = (blockIdx.x * blockDim.x + threadIdx.x) >> 6;
    int lane = threadIdx.x & 63;
    if (wid >= N) return;
    int n = __builtin_amdgcn_readfirstlane(wid);

    float di = dinv[n];
    int start = offs[n];
    int m = cnt[n];

    float2 a = ((const float2*)(x + (size_t)n * FEAT))[lane];
    float sl = di * di;
    float2 acc = make_float2(a.x * sl, a.y * sl);

    int i = 0;
    for (; i + 4 <= m; i += 4) {
        int s0 = (int)csr[start + i];
        int s1 = (int)csr[start + i + 1];
        int s2 = (int)csr[start + i + 2];
        int s3 = (int)csr[start + i + 3];
        float n0 = dinv[s0] * di, n1 = dinv[s1] * di, n2 = dinv[s2] * di, n3 = dinv[s3] * di;
        float2 v0 = ((const float2*)(x + (size_t)s0 * FEAT))[lane];
        float2 v1 = ((const float2*)(x + (size_t)s1 * FEAT))[lane];
        float2 v2 = ((const float2*)(x + (size_t)s2 * FEAT))[lane];
        float2 v3 = ((const float2*)(x + (size_t)s3 * FEAT))[lane];
        acc.x += n0 * v0.x; acc.y += n0 * v0.y;
        acc.x += n1 * v1.x; acc.y += n1 * v1.y;
        acc.x += n2 * v2.x; acc.y += n2 * v2.y;
        acc.x += n3 * v3.x; acc.y += n3 * v3.y;
    }
    for (; i < m; ++i) {
        int s0 = (int)csr[start + i];
        float n0 = dinv[s0] * di;
        float2 v0 = ((const float2*)(x + (size_t)s0 * FEAT))[lane];
        acc.x += n0 * v0.x; acc.y += n0 * v0.y;
    }
    ((float2*)(out + (size_t)n * FEAT))[lane] = acc;
}

__global__ __launch_bounds__(256) void k_gemm_inplace(float* __restrict__ out,
                                                      const float* __restrict__ W,
                                                      const float* __restrict__ b, int N) {
    __shared__ float Wl[FEAT * FEAT];
    int tid = threadIdx.x;
    for (int i = tid; i < FEAT * FEAT / 4; i += 256)
        ((float4*)Wl)[i] = ((const float4*)W)[i];
    __syncthreads();

    int j = tid & 127;
    int half = tid >> 7;
    int row0 = blockIdx.x * 16 + half * 8;
    row0 = __builtin_amdgcn_readfirstlane(row0);

    float bj = b[j];
    float acc[8];
#pragma unroll
    for (int r = 0; r < 8; ++r) acc[r] = bj;

    const float* Y = out + (size_t)row0 * FEAT;
    bool full = (row0 + 8 <= N);
    if (full) {
        for (int f4 = 0; f4 < FEAT; f4 += 4) {
            float w0 = Wl[(f4 + 0) * FEAT + j];
            float w1 = Wl[(f4 + 1) * FEAT + j];
            float w2 = Wl[(f4 + 2) * FEAT + j];
            float w3 = Wl[(f4 + 3) * FEAT + j];
#pragma unroll
            for (int r = 0; r < 8; ++r) {
                float4 y = *(const float4*)&Y[(size_t)r * FEAT + f4];
                acc[r] += w0 * y.x + w1 * y.y + w2 * y.z + w3 * y.w;
            }
        }
    } else {
        for (int f = 0; f < FEAT; ++f) {
            float w = Wl[f * FEAT + j];
            for (int r = 0; r < 8; ++r)
                if (row0 + r < N) acc[r] += w * Y[(size_t)r * FEAT + f];
        }
    }
    __syncthreads();
    if (full) {
#pragma unroll
        for (int r = 0; r < 8; ++r) out[(size_t)(row0 + r) * FEAT + j] = acc[r];
    } else {
        for (int r = 0; r < 8; ++r)
            if (row0 + r < N) out[(size_t)(row0 + r) * FEAT + j] = acc[r];
    }
}

__global__ void k_fill_direct(const int* __restrict__ src, const int* __restrict__ dst,
                              int* __restrict__ cur, unsigned int* __restrict__ csr, int E) {
    int e = blockIdx.x * blockDim.x + threadIdx.x;
    if (e < E) {
        int d = dst[e];
        int p = atomicAdd(&cur[d], 1);
        csr[p] = (unsigned int)src[e];
    }
}
__global__ void k_copy_i32(const int* __restrict__ a, int* __restrict__ b, int n) {
    int i = blockIdx.x * blockDim.x + threadIdx.x;
    if (i < n) b[i] = a[i];
}
__global__ void k_deg_initf(float* __restrict__ deg, int N) {
    int i = blockIdx.x * blockDim.x + threadIdx.x;
    if (i < N) deg[i] = 1.0f;
}
__global__ void k_deg_countf(const int* __restrict__ dst, float* __restrict__ deg, int E) {
    int i = blockIdx.x * blockDim.x + threadIdx.x;
    if (i < E) atomicAdd(&deg[dst[i]], 1.0f);
}
__global__ void k_rsqrtf_(float* __restrict__ deg, int N) {
    int i = blockIdx.x * blockDim.x + threadIdx.x;
    if (i < N) deg[i] = rsqrtf(deg[i]);
}
__global__ void k_selfloop(const float* __restrict__ x, const float* __restrict__ dinv,
                           float* __restrict__ out, int N) {
    int t = blockIdx.x * blockDim.x + threadIdx.x;
    int n = t >> 5, c = t & 31;
    if (n >= N) return;
    float s = dinv[n]; s *= s;
    float4 v = ((const float4*)(x + (size_t)n * FEAT))[c];
    v.x *= s; v.y *= s; v.z *= s; v.w *= s;
    ((float4*)(out + (size_t)n * FEAT))[c] = v;
}
__global__ void k_scatter(const int* __restrict__ src, const int* __restrict__ dst,
                          const float* __restrict__ dinv, const float* __restrict__ x,
                          float* __restrict__ out, int E) {
    long long gid = (long long)blockIdx.x * blockDim.x + threadIdx.x;
    long long e = gid >> 6;
    int lane = threadIdx.x & 63;
    if (e >= E) return;
    int s = src[e], d = dst[e];
    float nrm = dinv[s] * dinv[d];
    const float* xs = x + (size_t)s * FEAT;
    float* od = out + (size_t)d * FEAT;
    atomicAdd(&od[lane],      nrm * xs[lane]);
    atomicAdd(&od[lane + 64], nrm * xs[lane + 64]);
}

// ======================= launch =======================
extern "C" void kernel_launch(void* const* d_in, const int* in_sizes, int n_in,
                              void* d_out, int out_size, void* d_ws, size_t ws_size,
                              hipStream_t stream) {
    const float* x = (const float*)d_in[0];
    const int*   ei = (const int*)d_in[1];
    const float* W = (const float*)d_in[2];
    const float* b = (const float*)d_in[3];
    float* out = (float*)d_out;

    int N = in_sizes[0] / FEAT;
    int E = in_sizes[1] / 2;
    const int* src = ei;
    const int* dst = ei + E;

    const int bs = 256;
    int nTiles = (N + STILE - 1) / STILE;
    int NB = (N + BNODES - 1) >> BSH;
    int binGrid = (E + ATILE - 1) / ATILE;

    // ---- Tier A layout (256B-aligned bump allocation) ----
    size_t off = 0;
    auto take = [&](size_t bytes) {
        size_t r = off;
        off = (off + bytes + 255) & ~(size_t)255;
        return r;
    };
    size_t o_dinv  = take(4 * (size_t)N);
    size_t o_cnt   = take(4 * (size_t)N);
    size_t o_offs  = take(4 * (size_t)N);
    size_t o_bcnt  = take(4 * (size_t)NB);
    size_t o_boffs = take(4 * (size_t)(NB + 1));
    size_t o_cur   = take(4 * (size_t)NB);
    size_t o_pairs = take(4 * (size_t)E);
    size_t o_csr   = take(4 * (size_t)E);
    size_t o_xbf   = take(4 * (size_t)N * 64);
    size_t o_wbf   = take(2 * (size_t)FEAT * FEAT);
    size_t need_A = off;

    bool okNB = (NB <= MAXNB) && (N <= (1 << 24));
    bool can_A = okNB && (ws_size >= need_A);

    if (can_A) {
        char* base = (char*)d_ws;
        float* dinv = (float*)(base + o_dinv);
        int* cnt  = (int*)(base + o_cnt);
        int* offs = (int*)(base + o_offs);
        int* bCnt = (int*)(base + o_bcnt);
        int* bOffs= (int*)(base + o_boffs);
        int* cur  = (int*)(base + o_cur);
        unsigned int* pairs = (unsigned int*)(base + o_pairs);
        unsigned int* csr   = (unsigned int*)(base + o_csr);
        unsigned int* xbf   = (unsigned int*)(base + o_xbf);
        unsigned short* wbf = (unsigned short*)(base + o_wbf);

        long long n8 = (long long)N * (FEAT / 8);
        int zb = (NB + 255) / 256;
        int cb = (int)((n8 + 255) / 256);
        int wb = (FEAT * FEAT + 255) / 256;

        k_pre<<<zb + cb + wb, 256, 0, stream>>>(x, xbf, W, wbf, bCnt, n8, NB, zb, cb, wb);
        k_hist_bucket<<<binGrid, 256, 0, stream>>>(dst, bCnt, E, NB);
        k_scan_bucket<<<1, 256, 0, stream>>>(bCnt, bOffs, cur, NB, E);
        k_bin<<<binGrid, 256, 0, stream>>>(src, dst, cur, pairs, E, NB);
        k_fill_local2<<<NB, 256, 0, stream>>>(pairs, bOffs, csr, cnt, offs, dinv, N);
        k_agg_gemm<<<NB, 512, 0, stream>>>(xbf, dinv, offs, cnt, csr, wbf, b, out, N);
        return;
    }

    // ---- Tier B/C/D: earlier layouts and paths ----
    size_t need_direct = (4 * (size_t)N + nTiles + (size_t)E) * 4;
    size_t need_bin    = (4 * (size_t)N + nTiles + 2 * (size_t)E) * 4;
    size_t need_bf     = need_bin + (size_t)N * 64 * 4 + (size_t)FEAT * FEAT * 2 +
                         (size_t)N * 64 * 4;

    float* dinv = (float*)d_ws;
    int* cnt  = (int*)d_ws + N;
    int* offs = (int*)d_ws + 2 * (size_t)N;
    int* cur  = (int*)d_ws + 3 * (size_t)N;
    int* part = (int*)d_ws + 4 * (size_t)N;
    unsigned int* pairs = (unsigned int*)(part + nTiles);
    unsigned int* csr_bin = pairs + E;
    unsigned int* xbf = csr_bin + E;
    unsigned short* wbf = (unsigned short*)(xbf + (size_t)N * 64);
    unsigned int* aggbf = (unsigned int*)(wbf + (size_t)FEAT * FEAT);
    unsigned int* csr_dir = pairs;

    bool can_bin    = (ws_size >= need_bin) && okNB;
    bool can_bf     = can_bin && (ws_size >= need_bf);
    bool can_direct = (ws_size >= need_direct);

    if (can_bin || can_direct) {
        k_zero_i32<<<(N + bs - 1) / bs, bs, 0, stream>>>(cnt, N);
        k_count<<<(E + bs - 1) / bs, bs, 0, stream>>>(dst, cnt, E);
        k_dinv<<<(N + bs - 1) / bs, bs, 0, stream>>>(cnt, dinv, N);
        k_scan_partial<<<nTiles, 256, 0, stream>>>(cnt, part, N);
        k_scan_top<<<1, 256, 0, stream>>>(part, nTiles);
        k_scan_final<<<nTiles, 256, 0, stream>>>(cnt, part, offs, N);

        unsigned int* csr;
        if (can_bin) {
            csr = csr_bin;
            k_bucket_base<<<(NB + bs - 1) / bs, bs, 0, stream>>>(offs, cur, NB);
            k_bin<<<binGrid, 256, 0, stream>>>(src, dst, cur, pairs, E, NB);
            k_fill_local<<<NB, 256, 0, stream>>>(pairs, offs, csr, N, E);
        } else {
            csr = csr_dir;
            k_copy_i32<<<(N + bs - 1) / bs, bs, 0, stream>>>(offs, cur, N);
            k_fill_direct<<<(E + bs - 1) / bs, bs, 0, stream>>>(src, dst, cur, csr, E);
        }

        long long t_ag = (long long)N * 64;
        if (can_bf) {
            long long n8 = (long long)N * (FEAT / 8);
            k_cvt_bf16<<<(int)((n8 + bs - 1) / bs), bs, 0, stream>>>(x, xbf, n8);
            k_cvt_w<<<(FEAT * FEAT + bs - 1) / bs, bs, 0, stream>>>(W, wbf);
            k_aggregate_bf2<<<(int)((t_ag + bs - 1) / bs), bs, 0, stream>>>(
                xbf, dinv, offs, cnt, csr, aggbf, N);
            k_gemm_mfma2<<<(N + 127) / 128, 256, 0, stream>>>(
                (const unsigned short*)aggbf, wbf, b, out, N);
        } else {
            k_aggregate<<<(int)((t_ag + bs - 1) / bs), bs, 0, stream>>>(
                x, dinv, offs, cnt, csr, out, N);
            k_gemm_inplace<<<(N + 15) / 16, 256, 0, stream>>>(out, W, b, N);
        }
    } else {
        float* deg = (float*)d_ws;
        k_deg_initf<<<(N + bs - 1) / bs, bs, 0, stream>>>(deg, N);
        k_deg_countf<<<(E + bs - 1) / bs, bs, 0, stream>>>(dst, deg, E);
        k_rsqrtf_<<<(N + bs - 1) / bs, bs, 0, stream>>>(deg, N);
        long long t_sl = (long long)N * 32;
        k_selfloop<<<(int)((t_sl + bs - 1) / bs), bs, 0, stream>>>(x, deg, out, N);
        long long t_sc = (long long)E * 64;
        k_scatter<<<(int)((t_sc + bs - 1) / bs), bs, 0, stream>>>(src, dst, deg, x, out, E);
        k_gemm_inplace<<<(N + 15) / 16, 256, 0, stream>>>(out, W, b, N);
    }
}

// Round 9
// 308.161 us; speedup vs baseline: 1.1472x; 1.1472x over previous
//
#include <hip/hip_runtime.h>

#define FEAT 128
#define BSH 8
#define BNODES 256            // nodes per bucket = 1<<BSH
#define ATILE 4096            // edges per binning block
#define HTILE 16384           // edges per hist block (in k_pre)
#define MAXNB 1024            // bin/fill path requires NB <= 1024
#define MAXNB_A 512           // tier A (k_scan2) requires NB <= 512
#define STILE 1024

typedef __attribute__((ext_vector_type(8))) short bf16x8;
typedef __attribute__((ext_vector_type(4))) float f32x4;

// ======================= tiny kernels =======================
__global__ void k_zero_i32(int* __restrict__ p, int n) {
    int i = blockIdx.x * blockDim.x + threadIdx.x;
    if (i < n) p[i] = 0;
}

__global__ void k_count(const int* __restrict__ dst, int* __restrict__ cnt, int E) {
    int i = blockIdx.x * blockDim.x + threadIdx.x;
    if (i < E) atomicAdd(&cnt[dst[i]], 1);
}

__global__ void k_dinv(const int* __restrict__ cnt, float* __restrict__ dinv, int N) {
    int i = blockIdx.x * blockDim.x + threadIdx.x;
    if (i < N) dinv[i] = rsqrtf((float)cnt[i] + 1.0f);
}

__global__ void k_bucket_base(const int* __restrict__ offs, int* __restrict__ cur, int NB) {
    int b = blockIdx.x * blockDim.x + threadIdx.x;
    if (b < NB) cur[b] = offs[b << BSH];
}

__device__ inline unsigned int f2bf(float f) {
    unsigned int u = __float_as_uint(f);
    return (u + 0x7FFFu + ((u >> 16) & 1u)) >> 16;   // RNE
}

// ======================= K1: combined {cvt x | cvt W | bucket-hist partials} =======================
__global__ __launch_bounds__(256) void k_pre2(const float* __restrict__ x,
                                              unsigned int* __restrict__ xbf,
                                              const float* __restrict__ W,
                                              unsigned short* __restrict__ wt,
                                              const int* __restrict__ dst,
                                              int* __restrict__ bCntPart,
                                              long long n8, int E, int NB,
                                              int cb, int wb, int hb) {
    int blk = blockIdx.x;
    if (blk < cb) {
        long long i = (long long)blk * 256 + threadIdx.x;
        if (i >= n8) return;
        float4 a = ((const float4*)x)[i * 2];
        float4 c = ((const float4*)x)[i * 2 + 1];
        uint4 o;
        o.x = f2bf(a.x) | (f2bf(a.y) << 16);
        o.y = f2bf(a.z) | (f2bf(a.w) << 16);
        o.z = f2bf(c.x) | (f2bf(c.y) << 16);
        o.w = f2bf(c.z) | (f2bf(c.w) << 16);
        ((uint4*)xbf)[i] = o;
        return;
    }
    blk -= cb;
    if (blk < wb) {
        int i = blk * 256 + threadIdx.x;
        if (i >= FEAT * FEAT) return;
        int n = i >> 7, k = i & 127;
        wt[i] = (unsigned short)f2bf(W[k * FEAT + n]);
        return;
    }
    blk -= wb;
    if (blk < hb) {
        __shared__ int h[MAXNB_A];
        int tid = threadIdx.x;
        for (int i = tid; i < MAXNB_A; i += 256) h[i] = 0;
        __syncthreads();
        int base = blk * HTILE;
        int end = min(base + HTILE, E);
        for (int e = base + tid; e < end; e += 256)
            atomicAdd(&h[dst[e] >> BSH], 1);
        __syncthreads();
        int* outp = bCntPart + blk * MAXNB_A;
        for (int i = tid; i < MAXNB_A; i += 256) outp[i] = h[i];
    }
}

// ======================= K2: sum hist partials + exclusive scan -> bOffs, cur =======================
__global__ void k_scan2(const int* __restrict__ bCntPart, int hb, int NB, int E,
                        int* __restrict__ bOffs, int* __restrict__ cur) {
    __shared__ int c[MAXNB_A];
    __shared__ int s[256];
    int t = threadIdx.x;
    for (int i = t; i < MAXNB_A; i += 256) {
        int sum = 0;
        for (int p = 0; p < hb; ++p) sum += bCntPart[p * MAXNB_A + i];
        c[i] = sum;
    }
    __syncthreads();
    int carry = 0;
    for (int base = 0; base < MAXNB_A; base += 256) {
        int v = c[base + t];
        s[t] = v; __syncthreads();
        for (int o = 1; o < 256; o <<= 1) {
            int add = (t >= o) ? s[t - o] : 0;
            __syncthreads();
            s[t] += add;
            __syncthreads();
        }
        int ex = s[t] - v + carry;
        if (base + t < NB) { bOffs[base + t] = ex; cur[base + t] = ex; }
        __syncthreads();
        carry += s[255];
        __syncthreads();
    }
    if (t == 0) bOffs[NB] = E;
}

// standalone cvt kernels (tier B)
__global__ void k_cvt_bf16(const float* __restrict__ x, unsigned int* __restrict__ xbf,
                           long long n8) {
    long long i = (long long)blockIdx.x * blockDim.x + threadIdx.x;
    if (i >= n8) return;
    float4 a = ((const float4*)x)[i * 2];
    float4 c = ((const float4*)x)[i * 2 + 1];
    uint4 o;
    o.x = f2bf(a.x) | (f2bf(a.y) << 16);
    o.y = f2bf(a.z) | (f2bf(a.w) << 16);
    o.z = f2bf(c.x) | (f2bf(c.y) << 16);
    o.w = f2bf(c.z) | (f2bf(c.w) << 16);
    ((uint4*)xbf)[i] = o;
}
__global__ void k_cvt_w(const float* __restrict__ W, unsigned short* __restrict__ wt) {
    int i = blockIdx.x * blockDim.x + threadIdx.x;
    if (i >= FEAT * FEAT) return;
    int n = i >> 7, k = i & 127;
    wt[i] = (unsigned short)f2bf(W[k * FEAT + n]);
}

// ======================= N-scan (tier B only) =======================
__global__ void k_scan_partial(const int* __restrict__ cnt, int* __restrict__ part, int N) {
    __shared__ int s[256];
    int base = blockIdx.x * STILE;
    int t = threadIdx.x;
    int sum = 0;
#pragma unroll
    for (int k = 0; k < 4; ++k) {
        int i = base + t * 4 + k;
        if (i < N) sum += cnt[i];
    }
    s[t] = sum; __syncthreads();
    for (int off = 128; off > 0; off >>= 1) {
        if (t < off) s[t] += s[t + off];
        __syncthreads();
    }
    if (t == 0) part[blockIdx.x] = s[0];
}

__global__ void k_scan_top(int* __restrict__ part, int nTiles) {
    __shared__ int s[256];
    int t = threadIdx.x;
    int carry = 0;
    for (int base = 0; base < nTiles; base += 256) {
        int i = base + t;
        int v = (i < nTiles) ? part[i] : 0;
        s[t] = v; __syncthreads();
        for (int o = 1; o < 256; o <<= 1) {
            int add = (t >= o) ? s[t - o] : 0;
            __syncthreads();
            s[t] += add;
            __syncthreads();
        }
        if (i < nTiles) part[i] = (s[t] - v) + carry;
        __syncthreads();
        carry += s[255];
        __syncthreads();
    }
}

__global__ void k_scan_final(const int* __restrict__ cnt, const int* __restrict__ part,
                             int* __restrict__ offs, int N) {
    __shared__ int s[256];
    int base = blockIdx.x * STILE;
    int t = threadIdx.x;
    int v[4]; int sum = 0;
#pragma unroll
    for (int k = 0; k < 4; ++k) {
        int i = base + t * 4 + k;
        v[k] = (i < N) ? cnt[i] : 0;
        sum += v[k];
    }
    s[t] = sum; __syncthreads();
    for (int o = 1; o < 256; o <<= 1) {
        int add = (t >= o) ? s[t - o] : 0;
        __syncthreads();
        s[t] += add;
        __syncthreads();
    }
    int excl = (s[t] - sum) + part[blockIdx.x];
#pragma unroll
    for (int k = 0; k < 4; ++k) {
        int i = base + t * 4 + k;
        if (i < N) offs[i] = excl;
        excl += v[k];
    }
}

// ======================= pass A: bin edges by dst bucket =======================
__global__ __launch_bounds__(256) void k_bin(const int* __restrict__ src,
                                             const int* __restrict__ dst,
                                             int* __restrict__ cur,
                                             unsigned int* __restrict__ pairs,
                                             int E, int NB) {
    __shared__ int hist[MAXNB];
    __shared__ int tbase[MAXNB];
    __shared__ int sc[256];
    __shared__ unsigned int stM[ATILE];
    __shared__ unsigned short stB[ATILE];

    int tid = threadIdx.x;
    int tileBase = blockIdx.x * ATILE;
    int tileCnt = min(ATILE, E - tileBase);

    for (int i = tid; i < NB; i += 256) hist[i] = 0;
    __syncthreads();

    unsigned int pk[16]; unsigned short bk[16]; unsigned short rk[16];
#pragma unroll
    for (int k = 0; k < 16; ++k) {
        int e = tileBase + k * 256 + tid;
        if (e < E) {
            int s = src[e], d = dst[e];
            int b = d >> BSH;
            int r = atomicAdd(&hist[b], 1);
            pk[k] = (unsigned int)s | ((unsigned int)(d & (BNODES - 1)) << 24);
            bk[k] = (unsigned short)b;
            rk[k] = (unsigned short)r;
        }
    }
    __syncthreads();

    int per = (NB + 255) / 256;
    int myBase = tid * per;
    int partial = 0;
    for (int i = 0; i < per; ++i) {
        int idx = myBase + i;
        if (idx < NB) partial += hist[idx];
    }
    sc[tid] = partial;
    __syncthreads();
    for (int o = 1; o < 256; o <<= 1) {
        int add = (tid >= o) ? sc[tid - o] : 0;
        __syncthreads();
        sc[tid] += add;
        __syncthreads();
    }
    int run = (tid == 0) ? 0 : sc[tid - 1];
    for (int i = 0; i < per; ++i) {
        int idx = myBase + i;
        if (idx < NB) {
            int c = hist[idx];
            hist[idx] = run;
            if (c > 0) {
                int g = atomicAdd(&cur[idx], c);
                tbase[idx] = g - run;
            }
            run += c;
        }
    }
    __syncthreads();

#pragma unroll
    for (int k = 0; k < 16; ++k) {
        int e = tileBase + k * 256 + tid;
        if (e < E) {
            int slot = hist[bk[k]] + (int)rk[k];
            stM[slot] = pk[k];
            stB[slot] = bk[k];
        }
    }
    __syncthreads();

    for (int s = tid; s < tileCnt; s += 256) {
        int gpos = tbase[stB[s]] + s;
        pairs[gpos] = stM[s];
    }
}

// ======================= pass B: per-bucket cnt/offs/dinv + CSR fill (256 nodes/bucket) =======================
__global__ __launch_bounds__(256) void k_fill_local2(const unsigned int* __restrict__ pairs,
                                                     const int* __restrict__ bOffs,
                                                     unsigned int* __restrict__ csr,
                                                     int* __restrict__ g_cnt,
                                                     int* __restrict__ g_offs,
                                                     float* __restrict__ g_dinv,
                                                     int N) {
    __shared__ int lcnt[BNODES];
    __shared__ int lexcl[BNODES];
    __shared__ int lcur[BNODES];
    int b = blockIdx.x;
    int node0 = b << BSH;
    int nn = min(BNODES, N - node0);
    int tid = threadIdx.x;           // 256 threads == BNODES
    int bstart = bOffs[b], bend = bOffs[b + 1];

    lcnt[tid] = 0;
    __syncthreads();
    for (int i = bstart + tid; i < bend; i += 256)
        atomicAdd(&lcnt[pairs[i] >> 24], 1);
    __syncthreads();
    lexcl[tid] = lcnt[tid];
    __syncthreads();
    for (int o = 1; o < BNODES; o <<= 1) {
        int add = (tid >= o) ? lexcl[tid - o] : 0;
        __syncthreads();
        lexcl[tid] += add;
        __syncthreads();
    }
    {
        int ex = bstart + lexcl[tid] - lcnt[tid];
        lcur[tid] = ex;
        if (tid < nn) {
            g_cnt[node0 + tid] = lcnt[tid];
            g_offs[node0 + tid] = ex;
            g_dinv[node0 + tid] = rsqrtf((float)lcnt[tid] + 1.0f);
        }
    }
    __syncthreads();
    for (int i = bstart + tid; i < bend; i += 256) {
        unsigned int p = pairs[i];
        int dl = (int)(p >> 24);
        int pos = atomicAdd(&lcur[dl], 1);
        csr[pos] = p & 0xFFFFFFu;
    }
}

// tier B fill (uses N-scan offs)
__global__ __launch_bounds__(256) void k_fill_local(const unsigned int* __restrict__ pairs,
                                                    const int* __restrict__ offs,
                                                    unsigned int* __restrict__ csr,
                                                    int N, int E) {
    __shared__ int lcur[BNODES];
    int b = blockIdx.x;
    int node0 = b << BSH;
    int nn = min(BNODES, N - node0);
    int tid = threadIdx.x;
    for (int i = tid; i < nn; i += 256) lcur[i] = offs[node0 + i];
    __syncthreads();
    int start = offs[node0];
    int end = (node0 + BNODES >= N) ? E : offs[node0 + BNODES];
    for (int i = start + tid; i < end; i += 256) {
        unsigned int p = pairs[i];
        int dl = (int)(p >> 24);
        int pos = atomicAdd(&lcur[dl], 1);
        csr[pos] = p & 0xFFFFFFu;
    }
}

// ======================= aggregation (bf16 in, bf16 out): one wave per node =======================
__global__ __launch_bounds__(256) void k_aggregate_bf2(const unsigned int* __restrict__ xbf,
                                                       const float* __restrict__ dinv,
                                                       const int* __restrict__ offs,
                                                       const int* __restrict__ cnt,
                                                       const unsigned int* __restrict__ csr,
                                                       unsigned int* __restrict__ aggbf,
                                                       int N) {
    int wid = (blockIdx.x * blockDim.x + threadIdx.x) >> 6;
    int lane = threadIdx.x & 63;
    if (wid >= N) return;
    int n = __builtin_amdgcn_readfirstlane(wid);

    float di = dinv[n];
    int start = offs[n];
    int m = cnt[n];

    unsigned int wself = xbf[(size_t)n * 64 + lane];
    float sl = di * di;
    float2 acc = make_float2(sl * __uint_as_float(wself << 16),
                             sl * __uint_as_float(wself & 0xFFFF0000u));

    int i = 0;
    for (; i + 8 <= m; i += 8) {
        int s[8]; float nr[8]; unsigned int w[8];
#pragma unroll
        for (int u = 0; u < 8; ++u) s[u] = (int)csr[start + i + u];
#pragma unroll
        for (int u = 0; u < 8; ++u) w[u] = xbf[(size_t)s[u] * 64 + lane];
#pragma unroll
        for (int u = 0; u < 8; ++u) nr[u] = dinv[s[u]] * di;
#pragma unroll
        for (int u = 0; u < 8; ++u) {
            acc.x += nr[u] * __uint_as_float(w[u] << 16);
            acc.y += nr[u] * __uint_as_float(w[u] & 0xFFFF0000u);
        }
    }
    for (; i < m; ++i) {
        int s0 = (int)csr[start + i];
        float n0 = dinv[s0] * di;
        unsigned int w0 = xbf[(size_t)s0 * 64 + lane];
        acc.x += n0 * __uint_as_float(w0 << 16);
        acc.y += n0 * __uint_as_float(w0 & 0xFFFF0000u);
    }
    aggbf[(size_t)n * 64 + lane] = f2bf(acc.x) | (f2bf(acc.y) << 16);
}

// ======================= MFMA GEMM (bf16 A): out = aggbf @ Wt^T + b =======================
__global__ __launch_bounds__(256) void k_gemm_mfma2(const unsigned short* __restrict__ abf,
                                                    const unsigned short* __restrict__ wt,
                                                    const float* __restrict__ bias,
                                                    float* __restrict__ out, int N) {
    int tid = threadIdx.x;
    int wave = tid >> 6, l = tid & 63;
    int lm = l & 15, lg = l >> 4;
    int rowA = blockIdx.x * 128 + wave * 32;

    f32x4 acc[2][8];
#pragma unroll
    for (int mt = 0; mt < 2; ++mt)
#pragma unroll
        for (int nt = 0; nt < 8; ++nt)
            acc[mt][nt] = (f32x4){0.f, 0.f, 0.f, 0.f};

#pragma unroll
    for (int kk = 0; kk < 4; ++kk) {
        int k = kk * 32 + lg * 8;
        bf16x8 afr[2];
#pragma unroll
        for (int mt = 0; mt < 2; ++mt) {
            int r = rowA + mt * 16 + lm;
            if (r < N)
                afr[mt] = *(const bf16x8*)(abf + (size_t)r * FEAT + k);
            else
                afr[mt] = (bf16x8){0, 0, 0, 0, 0, 0, 0, 0};
        }
#pragma unroll
        for (int nt = 0; nt < 8; ++nt) {
            int col = nt * 16 + lm;
            bf16x8 bfr = *(const bf16x8*)(wt + (size_t)col * FEAT + k);
            acc[0][nt] = __builtin_amdgcn_mfma_f32_16x16x32_bf16(afr[0], bfr, acc[0][nt], 0, 0, 0);
            acc[1][nt] = __builtin_amdgcn_mfma_f32_16x16x32_bf16(afr[1], bfr, acc[1][nt], 0, 0, 0);
        }
    }

#pragma unroll
    for (int nt = 0; nt < 8; ++nt) {
        int col = nt * 16 + lm;
        float bv = bias[col];
#pragma unroll
        for (int mt = 0; mt < 2; ++mt) {
#pragma unroll
            for (int r = 0; r < 4; ++r) {
                int row = rowA + mt * 16 + lg * 4 + r;
                if (row < N) out[(size_t)row * FEAT + col] = acc[mt][nt][r] + bv;
            }
        }
    }
}

// ======================= tier B/C fallback kernels =======================
__global__ __launch_bounds__(256) void k_aggregate(const float* __restrict__ x,
                                                   const float* __restrict__ dinv,
                                                   const int* __restrict__ offs,
                                                   const int* __restrict__ cnt,
                                                   const unsigned int* __restrict__ csr,
                                                   float* __restrict__ out, int N) {
    int wid = (blockIdx.x * blockDim.x + threadIdx.x) >> 6;
    int lane = threadIdx.x & 63;
    if (wid >= N) return;
    int n = __builtin_amdgcn_readfirstlane(wid);

    float di = dinv[n];
    int start = offs[n];
    int m = cnt[n];

    float2 a = ((const float2*)(x + (size_t)n * FEAT))[lane];
    float sl = di * di;
    float2 acc = make_float2(a.x * sl, a.y * sl);

    int i = 0;
    for (; i + 4 <= m; i += 4) {
        int s0 = (int)csr[start + i];
        int s1 = (int)csr[start + i + 1];
        int s2 = (int)csr[start + i + 2];
        int s3 = (int)csr[start + i + 3];
        float n0 = dinv[s0] * di, n1 = dinv[s1] * di, n2 = dinv[s2] * di, n3 = dinv[s3] * di;
        float2 v0 = ((const float2*)(x + (size_t)s0 * FEAT))[lane];
        float2 v1 = ((const float2*)(x + (size_t)s1 * FEAT))[lane];
        float2 v2 = ((const float2*)(x + (size_t)s2 * FEAT))[lane];
        float2 v3 = ((const float2*)(x + (size_t)s3 * FEAT))[lane];
        acc.x += n0 * v0.x; acc.y += n0 * v0.y;
        acc.x += n1 * v1.x; acc.y += n1 * v1.y;
        acc.x += n2 * v2.x; acc.y += n2 * v2.y;
        acc.x += n3 * v3.x; acc.y += n3 * v3.y;
    }
    for (; i < m; ++i) {
        int s0 = (int)csr[start + i];
        float n0 = dinv[s0] * di;
        float2 v0 = ((const float2*)(x + (size_t)s0 * FEAT))[lane];
        acc.x += n0 * v0.x; acc.y += n0 * v0.y;
    }
    ((float2*)(out + (size_t)n * FEAT))[lane] = acc;
}

__global__ __launch_bounds__(256) void k_gemm_inplace(float* __restrict__ out,
                                                      const float* __restrict__ W,
                                                      const float* __restrict__ b, int N) {
    __shared__ float Wl[FEAT * FEAT];
    int tid = threadIdx.x;
    for (int i = tid; i < FEAT * FEAT / 4; i += 256)
        ((float4*)Wl)[i] = ((const float4*)W)[i];
    __syncthreads();

    int j = tid & 127;
    int half = tid >> 7;
    int row0 = blockIdx.x * 16 + half * 8;
    row0 = __builtin_amdgcn_readfirstlane(row0);

    float bj = b[j];
    float acc[8];
#pragma unroll
    for (int r = 0; r < 8; ++r) acc[r] = bj;

    const float* Y = out + (size_t)row0 * FEAT;
    bool full = (row0 + 8 <= N);
    if (full) {
        for (int f4 = 0; f4 < FEAT; f4 += 4) {
            float w0 = Wl[(f4 + 0) * FEAT + j];
            float w1 = Wl[(f4 + 1) * FEAT + j];
            float w2 = Wl[(f4 + 2) * FEAT + j];
            float w3 = Wl[(f4 + 3) * FEAT + j];
#pragma unroll
            for (int r = 0; r < 8; ++r) {
                float4 y = *(const float4*)&Y[(size_t)r * FEAT + f4];
                acc[r] += w0 * y.x + w1 * y.y + w2 * y.z + w3 * y.w;
            }
        }
    } else {
        for (int f = 0; f < FEAT; ++f) {
            float w = Wl[f * FEAT + j];
            for (int r = 0; r < 8; ++r)
                if (row0 + r < N) acc[r] += w * Y[(size_t)r * FEAT + f];
        }
    }
    __syncthreads();
    if (full) {
#pragma unroll
        for (int r = 0; r < 8; ++r) out[(size_t)(row0 + r) * FEAT + j] = acc[r];
    } else {
        for (int r = 0; r < 8; ++r)
            if (row0 + r < N) out[(size_t)(row0 + r) * FEAT + j] = acc[r];
    }
}

__global__ void k_fill_direct(const int* __restrict__ src, const int* __restrict__ dst,
                              int* __restrict__ cur, unsigned int* __restrict__ csr, int E) {
    int e = blockIdx.x * blockDim.x + threadIdx.x;
    if (e < E) {
        int d = dst[e];
        int p = atomicAdd(&cur[d], 1);
        csr[p] = (unsigned int)src[e];
    }
}
__global__ void k_copy_i32(const int* __restrict__ a, int* __restrict__ b, int n) {
    int i = blockIdx.x * blockDim.x + threadIdx.x;
    if (i < n) b[i] = a[i];
}
__global__ void k_deg_initf(float* __restrict__ deg, int N) {
    int i = blockIdx.x * blockDim.x + threadIdx.x;
    if (i < N) deg[i] = 1.0f;
}
__global__ void k_deg_countf(const int* __restrict__ dst, float* __restrict__ deg, int E) {
    int i = blockIdx.x * blockDim.x + threadIdx.x;
    if (i < E) atomicAdd(&deg[dst[i]], 1.0f);
}
__global__ void k_rsqrtf_(float* __restrict__ deg, int N) {
    int i = blockIdx.x * blockDim.x + threadIdx.x;
    if (i < N) deg[i] = rsqrtf(deg[i]);
}
__global__ void k_selfloop(const float* __restrict__ x, const float* __restrict__ dinv,
                           float* __restrict__ out, int N) {
    int t = blockIdx.x * blockDim.x + threadIdx.x;
    int n = t >> 5, c = t & 31;
    if (n >= N) return;
    float s = dinv[n]; s *= s;
    float4 v = ((const float4*)(x + (size_t)n * FEAT))[c];
    v.x *= s; v.y *= s; v.z *= s; v.w *= s;
    ((float4*)(out + (size_t)n * FEAT))[c] = v;
}
__global__ void k_scatter(const int* __restrict__ src, const int* __restrict__ dst,
                          const float* __restrict__ dinv, const float* __restrict__ x,
                          float* __restrict__ out, int E) {
    long long gid = (long long)blockIdx.x * blockDim.x + threadIdx.x;
    long long e = gid >> 6;
    int lane = threadIdx.x & 63;
    if (e >= E) return;
    int s = src[e], d = dst[e];
    float nrm = dinv[s] * dinv[d];
    const float* xs = x + (size_t)s * FEAT;
    float* od = out + (size_t)d * FEAT;
    atomicAdd(&od[lane],      nrm * xs[lane]);
    atomicAdd(&od[lane + 64], nrm * xs[lane + 64]);
}

// ======================= launch =======================
extern "C" void kernel_launch(void* const* d_in, const int* in_sizes, int n_in,
                              void* d_out, int out_size, void* d_ws, size_t ws_size,
                              hipStream_t stream) {
    const float* x = (const float*)d_in[0];
    const int*   ei = (const int*)d_in[1];
    const float* W = (const float*)d_in[2];
    const float* b = (const float*)d_in[3];
    float* out = (float*)d_out;

    int N = in_sizes[0] / FEAT;
    int E = in_sizes[1] / 2;
    const int* src = ei;
    const int* dst = ei + E;

    const int bs = 256;
    int nTiles = (N + STILE - 1) / STILE;
    int NB = (N + BNODES - 1) >> BSH;
    int binGrid = (E + ATILE - 1) / ATILE;
    int hb = (E + HTILE - 1) / HTILE;

    // ---- Tier A layout (256B-aligned bump allocation) ----
    size_t off = 0;
    auto take = [&](size_t bytes) {
        size_t r = off;
        off = (off + bytes + 255) & ~(size_t)255;
        return r;
    };
    size_t o_dinv  = take(4 * (size_t)N);
    size_t o_cnt   = take(4 * (size_t)N);
    size_t o_offs  = take(4 * (size_t)N);
    size_t o_bpart = take(4 * (size_t)hb * MAXNB_A);
    size_t o_boffs = take(4 * (size_t)(NB + 1));
    size_t o_cur   = take(4 * (size_t)NB);
    size_t o_pairs = take(4 * (size_t)E);
    size_t o_csr   = take(4 * (size_t)E);
    size_t o_xbf   = take(4 * (size_t)N * 64);
    size_t o_wbf   = take(2 * (size_t)FEAT * FEAT);
    size_t o_aggbf = take(4 * (size_t)N * 64);
    size_t need_A = off;

    bool okNB = (NB <= MAXNB) && (N <= (1 << 24));
    bool can_A = (NB <= MAXNB_A) && (N <= (1 << 24)) && (ws_size >= need_A);

    if (can_A) {
        char* base = (char*)d_ws;
        float* dinv = (float*)(base + o_dinv);
        int* cnt  = (int*)(base + o_cnt);
        int* offs = (int*)(base + o_offs);
        int* bPart= (int*)(base + o_bpart);
        int* bOffs= (int*)(base + o_boffs);
        int* cur  = (int*)(base + o_cur);
        unsigned int* pairs = (unsigned int*)(base + o_pairs);
        unsigned int* csr   = (unsigned int*)(base + o_csr);
        unsigned int* xbf   = (unsigned int*)(base + o_xbf);
        unsigned short* wbf = (unsigned short*)(base + o_wbf);
        unsigned int* aggbf = (unsigned int*)(base + o_aggbf);

        long long n8 = (long long)N * (FEAT / 8);
        int cb = (int)((n8 + 255) / 256);
        int wb = (FEAT * FEAT + 255) / 256;

        k_pre2<<<cb + wb + hb, 256, 0, stream>>>(x, xbf, W, wbf, dst, bPart,
                                                 n8, E, NB, cb, wb, hb);
        k_scan2<<<1, 256, 0, stream>>>(bPart, hb, NB, E, bOffs, cur);
        k_bin<<<binGrid, 256, 0, stream>>>(src, dst, cur, pairs, E, NB);
        k_fill_local2<<<NB, 256, 0, stream>>>(pairs, bOffs, csr, cnt, offs, dinv, N);

        long long t_ag = (long long)N * 64;
        k_aggregate_bf2<<<(int)((t_ag + bs - 1) / bs), bs, 0, stream>>>(
            xbf, dinv, offs, cnt, csr, aggbf, N);
        k_gemm_mfma2<<<(N + 127) / 128, 256, 0, stream>>>(
            (const unsigned short*)aggbf, wbf, b, out, N);
        return;
    }

    // ---- Tier B/C/D ----
    size_t need_direct = (4 * (size_t)N + nTiles + (size_t)E) * 4;
    size_t need_bin    = (4 * (size_t)N + nTiles + 2 * (size_t)E) * 4;
    size_t need_bf     = need_bin + (size_t)N * 64 * 4 + (size_t)FEAT * FEAT * 2 +
                         (size_t)N * 64 * 4;

    float* dinv = (float*)d_ws;
    int* cnt  = (int*)d_ws + N;
    int* offs = (int*)d_ws + 2 * (size_t)N;
    int* cur  = (int*)d_ws + 3 * (size_t)N;
    int* part = (int*)d_ws + 4 * (size_t)N;
    unsigned int* pairs = (unsigned int*)(part + nTiles);
    unsigned int* csr_bin = pairs + E;
    unsigned int* xbf = csr_bin + E;
    unsigned short* wbf = (unsigned short*)(xbf + (size_t)N * 64);
    unsigned int* aggbf = (unsigned int*)(wbf + (size_t)FEAT * FEAT);
    unsigned int* csr_dir = pairs;

    bool can_bin    = (ws_size >= need_bin) && okNB;
    bool can_bf     = can_bin && (ws_size >= need_bf);
    bool can_direct = (ws_size >= need_direct);

    if (can_bin || can_direct) {
        k_zero_i32<<<(N + bs - 1) / bs, bs, 0, stream>>>(cnt, N);
        k_count<<<(E + bs - 1) / bs, bs, 0, stream>>>(dst, cnt, E);
        k_dinv<<<(N + bs - 1) / bs, bs, 0, stream>>>(cnt, dinv, N);
        k_scan_partial<<<nTiles, 256, 0, stream>>>(cnt, part, N);
        k_scan_top<<<1, 256, 0, stream>>>(part, nTiles);
        k_scan_final<<<nTiles, 256, 0, stream>>>(cnt, part, offs, N);

        unsigned int* csr;
        if (can_bin) {
            csr = csr_bin;
            k_bucket_base<<<(NB + bs - 1) / bs, bs, 0, stream>>>(offs, cur, NB);
            k_bin<<<binGrid, 256, 0, stream>>>(src, dst, cur, pairs, E, NB);
            k_fill_local<<<NB, 256, 0, stream>>>(pairs, offs, csr, N, E);
        } else {
            csr = csr_dir;
            k_copy_i32<<<(N + bs - 1) / bs, bs, 0, stream>>>(offs, cur, N);
            k_fill_direct<<<(E + bs - 1) / bs, bs, 0, stream>>>(src, dst, cur, csr, E);
        }

        long long t_ag = (long long)N * 64;
        if (can_bf) {
            long long n8 = (long long)N * (FEAT / 8);
            k_cvt_bf16<<<(int)((n8 + bs - 1) / bs), bs, 0, stream>>>(x, xbf, n8);
            k_cvt_w<<<(FEAT * FEAT + bs - 1) / bs, bs, 0, stream>>>(W, wbf);
            k_aggregate_bf2<<<(int)((t_ag + bs - 1) / bs), bs, 0, stream>>>(
                xbf, dinv, offs, cnt, csr, aggbf, N);
            k_gemm_mfma2<<<(N + 127) / 128, 256, 0, stream>>>(
                (const unsigned short*)aggbf, wbf, b, out, N);
        } else {
            k_aggregate<<<(int)((t_ag + bs - 1) / bs), bs, 0, stream>>>(
                x, dinv, offs, cnt, csr, out, N);
            k_gemm_inplace<<<(N + 15) / 16, 256, 0, stream>>>(out, W, b, N);
        }
    } else {
        float* deg = (float*)d_ws;
        k_deg_initf<<<(N + bs - 1) / bs, bs, 0, stream>>>(deg, N);
        k_deg_countf<<<(E + bs - 1) / bs, bs, 0, stream>>>(dst, deg, E);
        k_rsqrtf_<<<(N + bs - 1) / bs, bs, 0, stream>>>(deg, N);
        long long t_sl = (long long)N * 32;
        k_selfloop<<<(int)((t_sl + bs - 1) / bs), bs, 0, stream>>>(x, deg, out, N);
        long long t_sc = (long long)E * 64;
        k_scatter<<<(int)((t_sc + bs - 1) / bs), bs, 0, stream>>>(src, dst, deg, x, out, E);
        k_gemm_inplace<<<(N + 15) / 16, 256, 0, stream>>>(out, W, b, N);
    }
}

// Round 10
// 262.976 us; speedup vs baseline: 1.3444x; 1.1718x over previous
//
#include <hip/hip_runtime.h>

#define FEAT 128
#define BSH 8
#define BNODES 256            // nodes per bucket = 1<<BSH
#define ATILE 4096            // edges per binning block
#define HTILE 16384           // edges per hist block (in k_pre2)
#define MAXNB 1024            // bin/fill path requires NB <= 1024
#define STILE 1024

typedef __attribute__((ext_vector_type(8))) short bf16x8;
typedef __attribute__((ext_vector_type(4))) float f32x4;

// ======================= tiny kernels =======================
__global__ void k_zero_i32(int* __restrict__ p, int n) {
    int i = blockIdx.x * blockDim.x + threadIdx.x;
    if (i < n) p[i] = 0;
}

__global__ void k_count(const int* __restrict__ dst, int* __restrict__ cnt, int E) {
    int i = blockIdx.x * blockDim.x + threadIdx.x;
    if (i < E) atomicAdd(&cnt[dst[i]], 1);
}

__global__ void k_dinv(const int* __restrict__ cnt, float* __restrict__ dinv, int N) {
    int i = blockIdx.x * blockDim.x + threadIdx.x;
    if (i < N) dinv[i] = rsqrtf((float)cnt[i] + 1.0f);
}

__global__ void k_bucket_base(const int* __restrict__ offs, int* __restrict__ cur, int NB) {
    int b = blockIdx.x * blockDim.x + threadIdx.x;
    if (b < NB) cur[b] = offs[b << BSH];
}

__device__ inline unsigned int f2bf(float f) {
    unsigned int u = __float_as_uint(f);
    return (u + 0x7FFFu + ((u >> 16) & 1u)) >> 16;   // RNE
}

// ======================= K1: combined {cvt x | cvt W | bucket-hist -> global atomics} =======================
// bCnt must be zeroed (memsetAsync) before this kernel.
__global__ __launch_bounds__(256) void k_pre2(const float* __restrict__ x,
                                              unsigned int* __restrict__ xbf,
                                              const float* __restrict__ W,
                                              unsigned short* __restrict__ wt,
                                              const int* __restrict__ dst,
                                              int* __restrict__ bCnt,
                                              long long n8, int E, int NB,
                                              int cb, int wb, int hb) {
    int blk = blockIdx.x;
    if (blk < cb) {
        long long i = (long long)blk * 256 + threadIdx.x;
        if (i >= n8) return;
        float4 a = ((const float4*)x)[i * 2];
        float4 c = ((const float4*)x)[i * 2 + 1];
        uint4 o;
        o.x = f2bf(a.x) | (f2bf(a.y) << 16);
        o.y = f2bf(a.z) | (f2bf(a.w) << 16);
        o.z = f2bf(c.x) | (f2bf(c.y) << 16);
        o.w = f2bf(c.z) | (f2bf(c.w) << 16);
        ((uint4*)xbf)[i] = o;
        return;
    }
    blk -= cb;
    if (blk < wb) {
        int i = blk * 256 + threadIdx.x;
        if (i >= FEAT * FEAT) return;
        int n = i >> 7, k = i & 127;
        wt[i] = (unsigned short)f2bf(W[k * FEAT + n]);
        return;
    }
    blk -= wb;
    if (blk < hb) {
        __shared__ int h[MAXNB];
        int tid = threadIdx.x;
        for (int i = tid; i < NB; i += 256) h[i] = 0;
        __syncthreads();
        int base = blk * HTILE;
        int end = min(base + HTILE, E);
        for (int e = base + tid; e < end; e += 256)
            atomicAdd(&h[dst[e] >> BSH], 1);
        __syncthreads();
        for (int i = tid; i < NB; i += 256)
            if (h[i]) atomicAdd(&bCnt[i], h[i]);
    }
}

// ======================= K2: exclusive scan of bCnt -> bOffs, cur (1 block, NB<=1024) =======================
__global__ void k_scan_bucket(const int* __restrict__ bCnt, int* __restrict__ bOffs,
                              int* __restrict__ cur, int NB, int E) {
    __shared__ int s[256];
    int t = threadIdx.x;
    int carry = 0;
    for (int base = 0; base < NB; base += 256) {
        int i = base + t;
        int v = (i < NB) ? bCnt[i] : 0;
        s[t] = v; __syncthreads();
        for (int o = 1; o < 256; o <<= 1) {
            int add = (t >= o) ? s[t - o] : 0;
            __syncthreads();
            s[t] += add;
            __syncthreads();
        }
        if (i < NB) { int ex = s[t] - v + carry; bOffs[i] = ex; cur[i] = ex; }
        __syncthreads();
        carry += s[255];
        __syncthreads();
    }
    if (t == 0) bOffs[NB] = E;
}

// standalone cvt kernels (tier B)
__global__ void k_cvt_bf16(const float* __restrict__ x, unsigned int* __restrict__ xbf,
                           long long n8) {
    long long i = (long long)blockIdx.x * blockDim.x + threadIdx.x;
    if (i >= n8) return;
    float4 a = ((const float4*)x)[i * 2];
    float4 c = ((const float4*)x)[i * 2 + 1];
    uint4 o;
    o.x = f2bf(a.x) | (f2bf(a.y) << 16);
    o.y = f2bf(a.z) | (f2bf(a.w) << 16);
    o.z = f2bf(c.x) | (f2bf(c.y) << 16);
    o.w = f2bf(c.z) | (f2bf(c.w) << 16);
    ((uint4*)xbf)[i] = o;
}
__global__ void k_cvt_w(const float* __restrict__ W, unsigned short* __restrict__ wt) {
    int i = blockIdx.x * blockDim.x + threadIdx.x;
    if (i >= FEAT * FEAT) return;
    int n = i >> 7, k = i & 127;
    wt[i] = (unsigned short)f2bf(W[k * FEAT + n]);
}

// ======================= N-scan (tier B only) =======================
__global__ void k_scan_partial(const int* __restrict__ cnt, int* __restrict__ part, int N) {
    __shared__ int s[256];
    int base = blockIdx.x * STILE;
    int t = threadIdx.x;
    int sum = 0;
#pragma unroll
    for (int k = 0; k < 4; ++k) {
        int i = base + t * 4 + k;
        if (i < N) sum += cnt[i];
    }
    s[t] = sum; __syncthreads();
    for (int off = 128; off > 0; off >>= 1) {
        if (t < off) s[t] += s[t + off];
        __syncthreads();
    }
    if (t == 0) part[blockIdx.x] = s[0];
}

__global__ void k_scan_top(int* __restrict__ part, int nTiles) {
    __shared__ int s[256];
    int t = threadIdx.x;
    int carry = 0;
    for (int base = 0; base < nTiles; base += 256) {
        int i = base + t;
        int v = (i < nTiles) ? part[i] : 0;
        s[t] = v; __syncthreads();
        for (int o = 1; o < 256; o <<= 1) {
            int add = (t >= o) ? s[t - o] : 0;
            __syncthreads();
            s[t] += add;
            __syncthreads();
        }
        if (i < nTiles) part[i] = (s[t] - v) + carry;
        __syncthreads();
        carry += s[255];
        __syncthreads();
    }
}

__global__ void k_scan_final(const int* __restrict__ cnt, const int* __restrict__ part,
                             int* __restrict__ offs, int N) {
    __shared__ int s[256];
    int base = blockIdx.x * STILE;
    int t = threadIdx.x;
    int v[4]; int sum = 0;
#pragma unroll
    for (int k = 0; k < 4; ++k) {
        int i = base + t * 4 + k;
        v[k] = (i < N) ? cnt[i] : 0;
        sum += v[k];
    }
    s[t] = sum; __syncthreads();
    for (int o = 1; o < 256; o <<= 1) {
        int add = (t >= o) ? s[t - o] : 0;
        __syncthreads();
        s[t] += add;
        __syncthreads();
    }
    int excl = (s[t] - sum) + part[blockIdx.x];
#pragma unroll
    for (int k = 0; k < 4; ++k) {
        int i = base + t * 4 + k;
        if (i < N) offs[i] = excl;
        excl += v[k];
    }
}

// ======================= pass A: bin edges by dst bucket =======================
__global__ __launch_bounds__(256) void k_bin(const int* __restrict__ src,
                                             const int* __restrict__ dst,
                                             int* __restrict__ cur,
                                             unsigned int* __restrict__ pairs,
                                             int E, int NB) {
    __shared__ int hist[MAXNB];
    __shared__ int tbase[MAXNB];
    __shared__ int sc[256];
    __shared__ unsigned int stM[ATILE];
    __shared__ unsigned short stB[ATILE];

    int tid = threadIdx.x;
    int tileBase = blockIdx.x * ATILE;
    int tileCnt = min(ATILE, E - tileBase);

    for (int i = tid; i < NB; i += 256) hist[i] = 0;
    __syncthreads();

    unsigned int pk[16]; unsigned short bk[16]; unsigned short rk[16];
#pragma unroll
    for (int k = 0; k < 16; ++k) {
        int e = tileBase + k * 256 + tid;
        if (e < E) {
            int s = src[e], d = dst[e];
            int b = d >> BSH;
            int r = atomicAdd(&hist[b], 1);
            pk[k] = (unsigned int)s | ((unsigned int)(d & (BNODES - 1)) << 24);
            bk[k] = (unsigned short)b;
            rk[k] = (unsigned short)r;
        }
    }
    __syncthreads();

    int per = (NB + 255) / 256;
    int myBase = tid * per;
    int partial = 0;
    for (int i = 0; i < per; ++i) {
        int idx = myBase + i;
        if (idx < NB) partial += hist[idx];
    }
    sc[tid] = partial;
    __syncthreads();
    for (int o = 1; o < 256; o <<= 1) {
        int add = (tid >= o) ? sc[tid - o] : 0;
        __syncthreads();
        sc[tid] += add;
        __syncthreads();
    }
    int run = (tid == 0) ? 0 : sc[tid - 1];
    for (int i = 0; i < per; ++i) {
        int idx = myBase + i;
        if (idx < NB) {
            int c = hist[idx];
            hist[idx] = run;
            if (c > 0) {
                int g = atomicAdd(&cur[idx], c);
                tbase[idx] = g - run;
            }
            run += c;
        }
    }
    __syncthreads();

#pragma unroll
    for (int k = 0; k < 16; ++k) {
        int e = tileBase + k * 256 + tid;
        if (e < E) {
            int slot = hist[bk[k]] + (int)rk[k];
            stM[slot] = pk[k];
            stB[slot] = bk[k];
        }
    }
    __syncthreads();

    for (int s = tid; s < tileCnt; s += 256) {
        int gpos = tbase[stB[s]] + s;
        pairs[gpos] = stM[s];
    }
}

// ======================= pass B: per-bucket cnt/offs/dinv + CSR fill (256 nodes/bucket) =======================
__global__ __launch_bounds__(256) void k_fill_local2(const unsigned int* __restrict__ pairs,
                                                     const int* __restrict__ bOffs,
                                                     unsigned int* __restrict__ csr,
                                                     int* __restrict__ g_cnt,
                                                     int* __restrict__ g_offs,
                                                     float* __restrict__ g_dinv,
                                                     int N) {
    __shared__ int lcnt[BNODES];
    __shared__ int lexcl[BNODES];
    __shared__ int lcur[BNODES];
    int b = blockIdx.x;
    int node0 = b << BSH;
    int nn = min(BNODES, N - node0);
    int tid = threadIdx.x;           // 256 threads == BNODES
    int bstart = bOffs[b], bend = bOffs[b + 1];

    lcnt[tid] = 0;
    __syncthreads();
    for (int i = bstart + tid; i < bend; i += 256)
        atomicAdd(&lcnt[pairs[i] >> 24], 1);
    __syncthreads();
    lexcl[tid] = lcnt[tid];
    __syncthreads();
    for (int o = 1; o < BNODES; o <<= 1) {
        int add = (tid >= o) ? lexcl[tid - o] : 0;
        __syncthreads();
        lexcl[tid] += add;
        __syncthreads();
    }
    {
        int ex = bstart + lexcl[tid] - lcnt[tid];
        lcur[tid] = ex;
        if (tid < nn) {
            g_cnt[node0 + tid] = lcnt[tid];
            g_offs[node0 + tid] = ex;
            g_dinv[node0 + tid] = rsqrtf((float)lcnt[tid] + 1.0f);
        }
    }
    __syncthreads();
    for (int i = bstart + tid; i < bend; i += 256) {
        unsigned int p = pairs[i];
        int dl = (int)(p >> 24);
        int pos = atomicAdd(&lcur[dl], 1);
        csr[pos] = p & 0xFFFFFFu;
    }
}

// tier B fill (uses N-scan offs)
__global__ __launch_bounds__(256) void k_fill_local(const unsigned int* __restrict__ pairs,
                                                    const int* __restrict__ offs,
                                                    unsigned int* __restrict__ csr,
                                                    int N, int E) {
    __shared__ int lcur[BNODES];
    int b = blockIdx.x;
    int node0 = b << BSH;
    int nn = min(BNODES, N - node0);
    int tid = threadIdx.x;
    for (int i = tid; i < nn; i += 256) lcur[i] = offs[node0 + i];
    __syncthreads();
    int start = offs[node0];
    int end = (node0 + BNODES >= N) ? E : offs[node0 + BNODES];
    for (int i = start + tid; i < end; i += 256) {
        unsigned int p = pairs[i];
        int dl = (int)(p >> 24);
        int pos = atomicAdd(&lcur[dl], 1);
        csr[pos] = p & 0xFFFFFFu;
    }
}

// ======================= aggregation (bf16 in, bf16 out): one wave per node =======================
__global__ __launch_bounds__(256) void k_aggregate_bf2(const unsigned int* __restrict__ xbf,
                                                       const float* __restrict__ dinv,
                                                       const int* __restrict__ offs,
                                                       const int* __restrict__ cnt,
                                                       const unsigned int* __restrict__ csr,
                                                       unsigned int* __restrict__ aggbf,
                                                       int N) {
    int wid = (blockIdx.x * blockDim.x + threadIdx.x) >> 6;
    int lane = threadIdx.x & 63;
    if (wid >= N) return;
    int n = __builtin_amdgcn_readfirstlane(wid);

    float di = dinv[n];
    int start = offs[n];
    int m = cnt[n];

    unsigned int wself = xbf[(size_t)n * 64 + lane];
    float sl = di * di;
    float2 acc = make_float2(sl * __uint_as_float(wself << 16),
                             sl * __uint_as_float(wself & 0xFFFF0000u));

    int i = 0;
    for (; i + 8 <= m; i += 8) {
        int s[8]; float nr[8]; unsigned int w[8];
#pragma unroll
        for (int u = 0; u < 8; ++u) s[u] = (int)csr[start + i + u];
#pragma unroll
        for (int u = 0; u < 8; ++u) w[u] = xbf[(size_t)s[u] * 64 + lane];
#pragma unroll
        for (int u = 0; u < 8; ++u) nr[u] = dinv[s[u]] * di;
#pragma unroll
        for (int u = 0; u < 8; ++u) {
            acc.x += nr[u] * __uint_as_float(w[u] << 16);
            acc.y += nr[u] * __uint_as_float(w[u] & 0xFFFF0000u);
        }
    }
    for (; i < m; ++i) {
        int s0 = (int)csr[start + i];
        float n0 = dinv[s0] * di;
        unsigned int w0 = xbf[(size_t)s0 * 64 + lane];
        acc.x += n0 * __uint_as_float(w0 << 16);
        acc.y += n0 * __uint_as_float(w0 & 0xFFFF0000u);
    }
    aggbf[(size_t)n * 64 + lane] = f2bf(acc.x) | (f2bf(acc.y) << 16);
}

// ======================= MFMA GEMM (bf16 A): out = aggbf @ Wt^T + b =======================
__global__ __launch_bounds__(256) void k_gemm_mfma2(const unsigned short* __restrict__ abf,
                                                    const unsigned short* __restrict__ wt,
                                                    const float* __restrict__ bias,
                                                    float* __restrict__ out, int N) {
    int tid = threadIdx.x;
    int wave = tid >> 6, l = tid & 63;
    int lm = l & 15, lg = l >> 4;
    int rowA = blockIdx.x * 128 + wave * 32;

    f32x4 acc[2][8];
#pragma unroll
    for (int mt = 0; mt < 2; ++mt)
#pragma unroll
        for (int nt = 0; nt < 8; ++nt)
            acc[mt][nt] = (f32x4){0.f, 0.f, 0.f, 0.f};

#pragma unroll
    for (int kk = 0; kk < 4; ++kk) {
        int k = kk * 32 + lg * 8;
        bf16x8 afr[2];
#pragma unroll
        for (int mt = 0; mt < 2; ++mt) {
            int r = rowA + mt * 16 + lm;
            if (r < N)
                afr[mt] = *(const bf16x8*)(abf + (size_t)r * FEAT + k);
            else
                afr[mt] = (bf16x8){0, 0, 0, 0, 0, 0, 0, 0};
        }
#pragma unroll
        for (int nt = 0; nt < 8; ++nt) {
            int col = nt * 16 + lm;
            bf16x8 bfr = *(const bf16x8*)(wt + (size_t)col * FEAT + k);
            acc[0][nt] = __builtin_amdgcn_mfma_f32_16x16x32_bf16(afr[0], bfr, acc[0][nt], 0, 0, 0);
            acc[1][nt] = __builtin_amdgcn_mfma_f32_16x16x32_bf16(afr[1], bfr, acc[1][nt], 0, 0, 0);
        }
    }

#pragma unroll
    for (int nt = 0; nt < 8; ++nt) {
        int col = nt * 16 + lm;
        float bv = bias[col];
#pragma unroll
        for (int mt = 0; mt < 2; ++mt) {
#pragma unroll
            for (int r = 0; r < 4; ++r) {
                int row = rowA + mt * 16 + lg * 4 + r;
                if (row < N) out[(size_t)row * FEAT + col] = acc[mt][nt][r] + bv;
            }
        }
    }
}

// ======================= tier B/C fallback kernels =======================
__global__ __launch_bounds__(256) void k_aggregate(const float* __restrict__ x,
                                                   const float* __restrict__ dinv,
                                                   const int* __restrict__ offs,
                                                   const int* __restrict__ cnt,
                                                   const unsigned int* __restrict__ csr,
                                                   float* __restrict__ out, int N) {
    int wid = (blockIdx.x * blockDim.x + threadIdx.x) >> 6;
    int lane = threadIdx.x & 63;
    if (wid >= N) return;
    int n = __builtin_amdgcn_readfirstlane(wid);

    float di = dinv[n];
    int start = offs[n];
    int m = cnt[n];

    float2 a = ((const float2*)(x + (size_t)n * FEAT))[lane];
    float sl = di * di;
    float2 acc = make_float2(a.x * sl, a.y * sl);

    int i = 0;
    for (; i + 4 <= m; i += 4) {
        int s0 = (int)csr[start + i];
        int s1 = (int)csr[start + i + 1];
        int s2 = (int)csr[start + i + 2];
        int s3 = (int)csr[start + i + 3];
        float n0 = dinv[s0] * di, n1 = dinv[s1] * di, n2 = dinv[s2] * di, n3 = dinv[s3] * di;
        float2 v0 = ((const float2*)(x + (size_t)s0 * FEAT))[lane];
        float2 v1 = ((const float2*)(x + (size_t)s1 * FEAT))[lane];
        float2 v2 = ((const float2*)(x + (size_t)s2 * FEAT))[lane];
        float2 v3 = ((const float2*)(x + (size_t)s3 * FEAT))[lane];
        acc.x += n0 * v0.x; acc.y += n0 * v0.y;
        acc.x += n1 * v1.x; acc.y += n1 * v1.y;
        acc.x += n2 * v2.x; acc.y += n2 * v2.y;
        acc.x += n3 * v3.x; acc.y += n3 * v3.y;
    }
    for (; i < m; ++i) {
        int s0 = (int)csr[start + i];
        float n0 = dinv[s0] * di;
        float2 v0 = ((const float2*)(x + (size_t)s0 * FEAT))[lane];
        acc.x += n0 * v0.x; acc.y += n0 * v0.y;
    }
    ((float2*)(out + (size_t)n * FEAT))[lane] = acc;
}

__global__ __launch_bounds__(256) void k_gemm_inplace(float* __restrict__ out,
                                                      const float* __restrict__ W,
                                                      const float* __restrict__ b, int N) {
    __shared__ float Wl[FEAT * FEAT];
    int tid = threadIdx.x;
    for (int i = tid; i < FEAT * FEAT / 4; i += 256)
        ((float4*)Wl)[i] = ((const float4*)W)[i];
    __syncthreads();

    int j = tid & 127;
    int half = tid >> 7;
    int row0 = blockIdx.x * 16 + half * 8;
    row0 = __builtin_amdgcn_readfirstlane(row0);

    float bj = b[j];
    float acc[8];
#pragma unroll
    for (int r = 0; r < 8; ++r) acc[r] = bj;

    const float* Y = out + (size_t)row0 * FEAT;
    bool full = (row0 + 8 <= N);
    if (full) {
        for (int f4 = 0; f4 < FEAT; f4 += 4) {
            float w0 = Wl[(f4 + 0) * FEAT + j];
            float w1 = Wl[(f4 + 1) * FEAT + j];
            float w2 = Wl[(f4 + 2) * FEAT + j];
            float w3 = Wl[(f4 + 3) * FEAT + j];
#pragma unroll
            for (int r = 0; r < 8; ++r) {
                float4 y = *(const float4*)&Y[(size_t)r * FEAT + f4];
                acc[r] += w0 * y.x + w1 * y.y + w2 * y.z + w3 * y.w;
            }
        }
    } else {
        for (int f = 0; f < FEAT; ++f) {
            float w = Wl[f * FEAT + j];
            for (int r = 0; r < 8; ++r)
                if (row0 + r < N) acc[r] += w * Y[(size_t)r * FEAT + f];
        }
    }
    __syncthreads();
    if (full) {
#pragma unroll
        for (int r = 0; r < 8; ++r) out[(size_t)(row0 + r) * FEAT + j] = acc[r];
    } else {
        for (int r = 0; r < 8; ++r)
            if (row0 + r < N) out[(size_t)(row0 + r) * FEAT + j] = acc[r];
    }
}

__global__ void k_fill_direct(const int* __restrict__ src, const int* __restrict__ dst,
                              int* __restrict__ cur, unsigned int* __restrict__ csr, int E) {
    int e = blockIdx.x * blockDim.x + threadIdx.x;
    if (e < E) {
        int d = dst[e];
        int p = atomicAdd(&cur[d], 1);
        csr[p] = (unsigned int)src[e];
    }
}
__global__ void k_copy_i32(const int* __restrict__ a, int* __restrict__ b, int n) {
    int i = blockIdx.x * blockDim.x + threadIdx.x;
    if (i < n) b[i] = a[i];
}
__global__ void k_deg_initf(float* __restrict__ deg, int N) {
    int i = blockIdx.x * blockDim.x + threadIdx.x;
    if (i < N) deg[i] = 1.0f;
}
__global__ void k_deg_countf(const int* __restrict__ dst, float* __restrict__ deg, int E) {
    int i = blockIdx.x * blockDim.x + threadIdx.x;
    if (i < E) atomicAdd(&deg[dst[i]], 1.0f);
}
__global__ void k_rsqrtf_(float* __restrict__ deg, int N) {
    int i = blockIdx.x * blockDim.x + threadIdx.x;
    if (i < N) deg[i] = rsqrtf(deg[i]);
}
__global__ void k_selfloop(const float* __restrict__ x, const float* __restrict__ dinv,
                           float* __restrict__ out, int N) {
    int t = blockIdx.x * blockDim.x + threadIdx.x;
    int n = t >> 5, c = t & 31;
    if (n >= N) return;
    float s = dinv[n]; s *= s;
    float4 v = ((const float4*)(x + (size_t)n * FEAT))[c];
    v.x *= s; v.y *= s; v.z *= s; v.w *= s;
    ((float4*)(out + (size_t)n * FEAT))[c] = v;
}
__global__ void k_scatter(const int* __restrict__ src, const int* __restrict__ dst,
                          const float* __restrict__ dinv, const float* __restrict__ x,
                          float* __restrict__ out, int E) {
    long long gid = (long long)blockIdx.x * blockDim.x + threadIdx.x;
    long long e = gid >> 6;
    int lane = threadIdx.x & 63;
    if (e >= E) return;
    int s = src[e], d = dst[e];
    float nrm = dinv[s] * dinv[d];
    const float* xs = x + (size_t)s * FEAT;
    float* od = out + (size_t)d * FEAT;
    atomicAdd(&od[lane],      nrm * xs[lane]);
    atomicAdd(&od[lane + 64], nrm * xs[lane + 64]);
}

// ======================= launch =======================
extern "C" void kernel_launch(void* const* d_in, const int* in_sizes, int n_in,
                              void* d_out, int out_size, void* d_ws, size_t ws_size,
                              hipStream_t stream) {
    const float* x = (const float*)d_in[0];
    const int*   ei = (const int*)d_in[1];
    const float* W = (const float*)d_in[2];
    const float* b = (const float*)d_in[3];
    float* out = (float*)d_out;

    int N = in_sizes[0] / FEAT;
    int E = in_sizes[1] / 2;
    const int* src = ei;
    const int* dst = ei + E;

    const int bs = 256;
    int nTiles = (N + STILE - 1) / STILE;
    int NB = (N + BNODES - 1) >> BSH;
    int binGrid = (E + ATILE - 1) / ATILE;
    int hb = (E + HTILE - 1) / HTILE;

    // ---- Tier A layout (256B-aligned bump allocation) ----
    size_t off = 0;
    auto take = [&](size_t bytes) {
        size_t r = off;
        off = (off + bytes + 255) & ~(size_t)255;
        return r;
    };
    size_t o_dinv  = take(4 * (size_t)N);
    size_t o_cnt   = take(4 * (size_t)N);
    size_t o_offs  = take(4 * (size_t)N);
    size_t o_bcnt  = take(4 * (size_t)NB);
    size_t o_boffs = take(4 * (size_t)(NB + 1));
    size_t o_cur   = take(4 * (size_t)NB);
    size_t o_pairs = take(4 * (size_t)E);
    size_t o_csr   = take(4 * (size_t)E);
    size_t o_xbf   = take(4 * (size_t)N * 64);
    size_t o_wbf   = take(2 * (size_t)FEAT * FEAT);
    size_t o_aggbf = take(4 * (size_t)N * 64);
    size_t need_A = off;

    bool okNB = (NB <= MAXNB) && (N <= (1 << 24));
    bool can_A = okNB && (ws_size >= need_A);

    if (can_A) {
        char* base = (char*)d_ws;
        float* dinv = (float*)(base + o_dinv);
        int* cnt  = (int*)(base + o_cnt);
        int* offs = (int*)(base + o_offs);
        int* bCnt = (int*)(base + o_bcnt);
        int* bOffs= (int*)(base + o_boffs);
        int* cur  = (int*)(base + o_cur);
        unsigned int* pairs = (unsigned int*)(base + o_pairs);
        unsigned int* csr   = (unsigned int*)(base + o_csr);
        unsigned int* xbf   = (unsigned int*)(base + o_xbf);
        unsigned short* wbf = (unsigned short*)(base + o_wbf);
        unsigned int* aggbf = (unsigned int*)(base + o_aggbf);

        long long n8 = (long long)N * (FEAT / 8);
        int cb = (int)((n8 + 255) / 256);
        int wb = (FEAT * FEAT + 255) / 256;

        hipMemsetAsync(bCnt, 0, 4 * (size_t)NB, stream);
        k_pre2<<<cb + wb + hb, 256, 0, stream>>>(x, xbf, W, wbf, dst, bCnt,
                                                 n8, E, NB, cb, wb, hb);
        k_scan_bucket<<<1, 256, 0, stream>>>(bCnt, bOffs, cur, NB, E);
        k_bin<<<binGrid, 256, 0, stream>>>(src, dst, cur, pairs, E, NB);
        k_fill_local2<<<NB, 256, 0, stream>>>(pairs, bOffs, csr, cnt, offs, dinv, N);

        long long t_ag = (long long)N * 64;
        k_aggregate_bf2<<<(int)((t_ag + bs - 1) / bs), bs, 0, stream>>>(
            xbf, dinv, offs, cnt, csr, aggbf, N);
        k_gemm_mfma2<<<(N + 127) / 128, 256, 0, stream>>>(
            (const unsigned short*)aggbf, wbf, b, out, N);
        return;
    }

    // ---- Tier B/C/D ----
    size_t need_direct = (4 * (size_t)N + nTiles + (size_t)E) * 4;
    size_t need_bin    = (4 * (size_t)N + nTiles + 2 * (size_t)E) * 4;
    size_t need_bf     = need_bin + (size_t)N * 64 * 4 + (size_t)FEAT * FEAT * 2 +
                         (size_t)N * 64 * 4;

    float* dinv = (float*)d_ws;
    int* cnt  = (int*)d_ws + N;
    int* offs = (int*)d_ws + 2 * (size_t)N;
    int* cur  = (int*)d_ws + 3 * (size_t)N;
    int* part = (int*)d_ws + 4 * (size_t)N;
    unsigned int* pairs = (unsigned int*)(part + nTiles);
    unsigned int* csr_bin = pairs + E;
    unsigned int* xbf = csr_bin + E;
    unsigned short* wbf = (unsigned short*)(xbf + (size_t)N * 64);
    unsigned int* aggbf = (unsigned int*)(wbf + (size_t)FEAT * FEAT);
    unsigned int* csr_dir = pairs;

    bool can_bin    = (ws_size >= need_bin) && okNB;
    bool can_bf     = can_bin && (ws_size >= need_bf);
    bool can_direct = (ws_size >= need_direct);

    if (can_bin || can_direct) {
        k_zero_i32<<<(N + bs - 1) / bs, bs, 0, stream>>>(cnt, N);
        k_count<<<(E + bs - 1) / bs, bs, 0, stream>>>(dst, cnt, E);
        k_dinv<<<(N + bs - 1) / bs, bs, 0, stream>>>(cnt, dinv, N);
        k_scan_partial<<<nTiles, 256, 0, stream>>>(cnt, part, N);
        k_scan_top<<<1, 256, 0, stream>>>(part, nTiles);
        k_scan_final<<<nTiles, 256, 0, stream>>>(cnt, part, offs, N);

        unsigned int* csr;
        if (can_bin) {
            csr = csr_bin;
            k_bucket_base<<<(NB + bs - 1) / bs, bs, 0, stream>>>(offs, cur, NB);
            k_bin<<<binGrid, 256, 0, stream>>>(src, dst, cur, pairs, E, NB);
            k_fill_local<<<NB, 256, 0, stream>>>(pairs, offs, csr, N, E);
        } else {
            csr = csr_dir;
            k_copy_i32<<<(N + bs - 1) / bs, bs, 0, stream>>>(offs, cur, N);
            k_fill_direct<<<(E + bs - 1) / bs, bs, 0, stream>>>(src, dst, cur, csr, E);
        }

        long long t_ag = (long long)N * 64;
        if (can_bf) {
            long long n8 = (long long)N * (FEAT / 8);
            k_cvt_bf16<<<(int)((n8 + bs - 1) / bs), bs, 0, stream>>>(x, xbf, n8);
            k_cvt_w<<<(FEAT * FEAT + bs - 1) / bs, bs, 0, stream>>>(W, wbf);
            k_aggregate_bf2<<<(int)((t_ag + bs - 1) / bs), bs, 0, stream>>>(
                xbf, dinv, offs, cnt, csr, aggbf, N);
            k_gemm_mfma2<<<(N + 127) / 128, 256, 0, stream>>>(
                (const unsigned short*)aggbf, wbf, b, out, N);
        } else {
            k_aggregate<<<(int)((t_ag + bs - 1) / bs), bs, 0, stream>>>(
                x, dinv, offs, cnt, csr, out, N);
            k_gemm_inplace<<<(N + 15) / 16, 256, 0, stream>>>(out, W, b, N);
        }
    } else {
        float* deg = (float*)d_ws;
        k_deg_initf<<<(N + bs - 1) / bs, bs, 0, stream>>>(deg, N);
        k_deg_countf<<<(E + bs - 1) / bs, bs, 0, stream>>>(dst, deg, E);
        k_rsqrtf_<<<(N + bs - 1) / bs, bs, 0, stream>>>(deg, N);
        long long t_sl = (long long)N * 32;
        k_selfloop<<<(int)((t_sl + bs - 1) / bs), bs, 0, stream>>>(x, deg, out, N);
        long long t_sc = (long long)E * 64;
        k_scatter<<<(int)((t_sc + bs - 1) / bs), bs, 0, stream>>>(src, dst, deg, x, out, E);
        k_gemm_inplace<<<(N + 15) / 16, 256, 0, stream>>>(out, W, b, N);
    }
}

// Round 11
// 257.853 us; speedup vs baseline: 1.3711x; 1.0199x over previous
//
#include <hip/hip_runtime.h>

#define FEAT 128
#define BSH 8
#define BNODES 256            // nodes per bucket = 1<<BSH
#define ATILE 4096            // edges per binning block
#define HTILE 16384           // edges per hist block (in k_pre2)
#define MAXNB 1024            // bin/fill path requires NB <= 1024
#define STILE 1024

typedef __attribute__((ext_vector_type(8))) short bf16x8;
typedef __attribute__((ext_vector_type(4))) float f32x4;

// ======================= tiny kernels =======================
__global__ void k_zero_i32(int* __restrict__ p, int n) {
    int i = blockIdx.x * blockDim.x + threadIdx.x;
    if (i < n) p[i] = 0;
}

__global__ void k_count(const int* __restrict__ dst, int* __restrict__ cnt, int E) {
    int i = blockIdx.x * blockDim.x + threadIdx.x;
    if (i < E) atomicAdd(&cnt[dst[i]], 1);
}

__global__ void k_dinv(const int* __restrict__ cnt, float* __restrict__ dinv, int N) {
    int i = blockIdx.x * blockDim.x + threadIdx.x;
    if (i < N) dinv[i] = rsqrtf((float)cnt[i] + 1.0f);
}

__global__ void k_bucket_base(const int* __restrict__ offs, int* __restrict__ cur, int NB) {
    int b = blockIdx.x * blockDim.x + threadIdx.x;
    if (b < NB) cur[b] = offs[b << BSH];
}

__device__ inline unsigned int f2bf(float f) {
    unsigned int u = __float_as_uint(f);
    return (u + 0x7FFFu + ((u >> 16) & 1u)) >> 16;   // RNE
}

// ======================= K1: combined {cvt x | cvt W | bucket-hist -> global atomics} =======================
// bCnt must be zeroed (memsetAsync) before this kernel.
__global__ __launch_bounds__(256) void k_pre2(const float* __restrict__ x,
                                              unsigned int* __restrict__ xbf,
                                              const float* __restrict__ W,
                                              unsigned short* __restrict__ wt,
                                              const int* __restrict__ dst,
                                              int* __restrict__ bCnt,
                                              long long n8, int E, int NB,
                                              int cb, int wb, int hb) {
    int blk = blockIdx.x;
    if (blk < cb) {
        long long i = (long long)blk * 256 + threadIdx.x;
        if (i >= n8) return;
        float4 a = ((const float4*)x)[i * 2];
        float4 c = ((const float4*)x)[i * 2 + 1];
        uint4 o;
        o.x = f2bf(a.x) | (f2bf(a.y) << 16);
        o.y = f2bf(a.z) | (f2bf(a.w) << 16);
        o.z = f2bf(c.x) | (f2bf(c.y) << 16);
        o.w = f2bf(c.z) | (f2bf(c.w) << 16);
        ((uint4*)xbf)[i] = o;
        return;
    }
    blk -= cb;
    if (blk < wb) {
        int i = blk * 256 + threadIdx.x;
        if (i >= FEAT * FEAT) return;
        int n = i >> 7, k = i & 127;
        wt[i] = (unsigned short)f2bf(W[k * FEAT + n]);
        return;
    }
    blk -= wb;
    if (blk < hb) {
        __shared__ int h[MAXNB];
        int tid = threadIdx.x;
        for (int i = tid; i < NB; i += 256) h[i] = 0;
        __syncthreads();
        int base = blk * HTILE;
        int end = min(base + HTILE, E);
        for (int e = base + tid; e < end; e += 256)
            atomicAdd(&h[dst[e] >> BSH], 1);
        __syncthreads();
        for (int i = tid; i < NB; i += 256)
            if (h[i]) atomicAdd(&bCnt[i], h[i]);
    }
}

// standalone cvt kernels (tier B)
__global__ void k_cvt_bf16(const float* __restrict__ x, unsigned int* __restrict__ xbf,
                           long long n8) {
    long long i = (long long)blockIdx.x * blockDim.x + threadIdx.x;
    if (i >= n8) return;
    float4 a = ((const float4*)x)[i * 2];
    float4 c = ((const float4*)x)[i * 2 + 1];
    uint4 o;
    o.x = f2bf(a.x) | (f2bf(a.y) << 16);
    o.y = f2bf(a.z) | (f2bf(a.w) << 16);
    o.z = f2bf(c.x) | (f2bf(c.y) << 16);
    o.w = f2bf(c.z) | (f2bf(c.w) << 16);
    ((uint4*)xbf)[i] = o;
}
__global__ void k_cvt_w(const float* __restrict__ W, unsigned short* __restrict__ wt) {
    int i = blockIdx.x * blockDim.x + threadIdx.x;
    if (i >= FEAT * FEAT) return;
    int n = i >> 7, k = i & 127;
    wt[i] = (unsigned short)f2bf(W[k * FEAT + n]);
}

// ======================= K2 (tier A): bin with local bucket-scan; no separate scan kernel ====
// cur[] must be zeroed. bCnt is the final global bucket histogram.
// Block 0 additionally publishes bOffs (exclusive scan of bCnt) + bOffs[NB]=E for k_fill.
__global__ __launch_bounds__(256) void k_bin2(const int* __restrict__ src,
                                              const int* __restrict__ dst,
                                              const int* __restrict__ bCnt,
                                              int* __restrict__ cur,
                                              int* __restrict__ bOffs,
                                              unsigned int* __restrict__ pairs,
                                              int E, int NB) {
    __shared__ int hist[MAXNB];
    __shared__ int tbase[MAXNB];
    __shared__ int sc[256];
    __shared__ int sc2[256];
    __shared__ unsigned int stM[ATILE];
    __shared__ unsigned short stB[ATILE];

    int tid = threadIdx.x;
    int tileBase = blockIdx.x * ATILE;
    int tileCnt = min(ATILE, E - tileBase);

    for (int i = tid; i < NB; i += 256) hist[i] = 0;
    __syncthreads();

    unsigned int pk[16]; unsigned short bk[16]; unsigned short rk[16];
#pragma unroll
    for (int k = 0; k < 16; ++k) {
        int e = tileBase + k * 256 + tid;
        if (e < E) {
            int s = src[e], d = dst[e];
            int b = d >> BSH;
            int r = atomicAdd(&hist[b], 1);
            pk[k] = (unsigned int)s | ((unsigned int)(d & (BNODES - 1)) << 24);
            bk[k] = (unsigned short)b;
            rk[k] = (unsigned short)r;
        }
    }
    __syncthreads();

    // dual scan: local tile hist (slots) + global bCnt (bucket bases)
    int per = (NB + 255) / 256;
    int myBase = tid * per;
    int ph = 0, pg = 0;
    for (int i = 0; i < per; ++i) {
        int idx = myBase + i;
        if (idx < NB) { ph += hist[idx]; pg += bCnt[idx]; }
    }
    sc[tid] = ph; sc2[tid] = pg;
    __syncthreads();
    for (int o = 1; o < 256; o <<= 1) {
        int ah = (tid >= o) ? sc[tid - o] : 0;
        int ag = (tid >= o) ? sc2[tid - o] : 0;
        __syncthreads();
        sc[tid] += ah; sc2[tid] += ag;
        __syncthreads();
    }
    int run_h = (tid == 0) ? 0 : sc[tid - 1];
    int run_g = (tid == 0) ? 0 : sc2[tid - 1];
    bool pub = (blockIdx.x == 0);
    for (int i = 0; i < per; ++i) {
        int idx = myBase + i;
        if (idx < NB) {
            int ch = hist[idx];
            hist[idx] = run_h;
            if (pub) bOffs[idx] = run_g;
            if (ch > 0) {
                int g = run_g + atomicAdd(&cur[idx], ch);
                tbase[idx] = g - run_h;
            }
            run_h += ch;
            run_g += bCnt[idx];
        }
    }
    if (pub && tid == 0) bOffs[NB] = E;
    __syncthreads();

#pragma unroll
    for (int k = 0; k < 16; ++k) {
        int e = tileBase + k * 256 + tid;
        if (e < E) {
            int slot = hist[bk[k]] + (int)rk[k];
            stM[slot] = pk[k];
            stB[slot] = bk[k];
        }
    }
    __syncthreads();

    for (int s = tid; s < tileCnt; s += 256) {
        int gpos = tbase[stB[s]] + s;
        pairs[gpos] = stM[s];
    }
}

// ======================= tier B bin (cur pre-initialized to bucket bases) =======================
__global__ __launch_bounds__(256) void k_bin(const int* __restrict__ src,
                                             const int* __restrict__ dst,
                                             int* __restrict__ cur,
                                             unsigned int* __restrict__ pairs,
                                             int E, int NB) {
    __shared__ int hist[MAXNB];
    __shared__ int tbase[MAXNB];
    __shared__ int sc[256];
    __shared__ unsigned int stM[ATILE];
    __shared__ unsigned short stB[ATILE];

    int tid = threadIdx.x;
    int tileBase = blockIdx.x * ATILE;
    int tileCnt = min(ATILE, E - tileBase);

    for (int i = tid; i < NB; i += 256) hist[i] = 0;
    __syncthreads();

    unsigned int pk[16]; unsigned short bk[16]; unsigned short rk[16];
#pragma unroll
    for (int k = 0; k < 16; ++k) {
        int e = tileBase + k * 256 + tid;
        if (e < E) {
            int s = src[e], d = dst[e];
            int b = d >> BSH;
            int r = atomicAdd(&hist[b], 1);
            pk[k] = (unsigned int)s | ((unsigned int)(d & (BNODES - 1)) << 24);
            bk[k] = (unsigned short)b;
            rk[k] = (unsigned short)r;
        }
    }
    __syncthreads();

    int per = (NB + 255) / 256;
    int myBase = tid * per;
    int partial = 0;
    for (int i = 0; i < per; ++i) {
        int idx = myBase + i;
        if (idx < NB) partial += hist[idx];
    }
    sc[tid] = partial;
    __syncthreads();
    for (int o = 1; o < 256; o <<= 1) {
        int add = (tid >= o) ? sc[tid - o] : 0;
        __syncthreads();
        sc[tid] += add;
        __syncthreads();
    }
    int run = (tid == 0) ? 0 : sc[tid - 1];
    for (int i = 0; i < per; ++i) {
        int idx = myBase + i;
        if (idx < NB) {
            int c = hist[idx];
            hist[idx] = run;
            if (c > 0) {
                int g = atomicAdd(&cur[idx], c);
                tbase[idx] = g - run;
            }
            run += c;
        }
    }
    __syncthreads();

#pragma unroll
    for (int k = 0; k < 16; ++k) {
        int e = tileBase + k * 256 + tid;
        if (e < E) {
            int slot = hist[bk[k]] + (int)rk[k];
            stM[slot] = pk[k];
            stB[slot] = bk[k];
        }
    }
    __syncthreads();

    for (int s = tid; s < tileCnt; s += 256) {
        int gpos = tbase[stB[s]] + s;
        pairs[gpos] = stM[s];
    }
}

// ======================= N-scan (tier B only) =======================
__global__ void k_scan_partial(const int* __restrict__ cnt, int* __restrict__ part, int N) {
    __shared__ int s[256];
    int base = blockIdx.x * STILE;
    int t = threadIdx.x;
    int sum = 0;
#pragma unroll
    for (int k = 0; k < 4; ++k) {
        int i = base + t * 4 + k;
        if (i < N) sum += cnt[i];
    }
    s[t] = sum; __syncthreads();
    for (int off = 128; off > 0; off >>= 1) {
        if (t < off) s[t] += s[t + off];
        __syncthreads();
    }
    if (t == 0) part[blockIdx.x] = s[0];
}

__global__ void k_scan_top(int* __restrict__ part, int nTiles) {
    __shared__ int s[256];
    int t = threadIdx.x;
    int carry = 0;
    for (int base = 0; base < nTiles; base += 256) {
        int i = base + t;
        int v = (i < nTiles) ? part[i] : 0;
        s[t] = v; __syncthreads();
        for (int o = 1; o < 256; o <<= 1) {
            int add = (t >= o) ? s[t - o] : 0;
            __syncthreads();
            s[t] += add;
            __syncthreads();
        }
        if (i < nTiles) part[i] = (s[t] - v) + carry;
        __syncthreads();
        carry += s[255];
        __syncthreads();
    }
}

__global__ void k_scan_final(const int* __restrict__ cnt, const int* __restrict__ part,
                             int* __restrict__ offs, int N) {
    __shared__ int s[256];
    int base = blockIdx.x * STILE;
    int t = threadIdx.x;
    int v[4]; int sum = 0;
#pragma unroll
    for (int k = 0; k < 4; ++k) {
        int i = base + t * 4 + k;
        v[k] = (i < N) ? cnt[i] : 0;
        sum += v[k];
    }
    s[t] = sum; __syncthreads();
    for (int o = 1; o < 256; o <<= 1) {
        int add = (t >= o) ? s[t - o] : 0;
        __syncthreads();
        s[t] += add;
        __syncthreads();
    }
    int excl = (s[t] - sum) + part[blockIdx.x];
#pragma unroll
    for (int k = 0; k < 4; ++k) {
        int i = base + t * 4 + k;
        if (i < N) offs[i] = excl;
        excl += v[k];
    }
}

// ======================= pass B: per-bucket cnt/offs/dinv + CSR fill (512 threads) ============
__global__ __launch_bounds__(512) void k_fill_local2(const unsigned int* __restrict__ pairs,
                                                     const int* __restrict__ bOffs,
                                                     unsigned int* __restrict__ csr,
                                                     int* __restrict__ g_cnt,
                                                     int* __restrict__ g_offs,
                                                     float* __restrict__ g_dinv,
                                                     int N) {
    __shared__ int lcnt[BNODES];
    __shared__ int lexcl[BNODES];
    __shared__ int lcur[BNODES];
    int b = blockIdx.x;
    int node0 = b << BSH;
    int nn = min(BNODES, N - node0);
    int tid = threadIdx.x;           // 0..511; BNODES == 256
    int bstart = bOffs[b], bend = bOffs[b + 1];

    if (tid < BNODES) lcnt[tid] = 0;
    __syncthreads();
    for (int i = bstart + tid; i < bend; i += 512)
        atomicAdd(&lcnt[pairs[i] >> 24], 1);
    __syncthreads();
    if (tid < BNODES) lexcl[tid] = lcnt[tid];
    __syncthreads();
    for (int o = 1; o < BNODES; o <<= 1) {
        int add = (tid < BNODES && tid >= o) ? lexcl[tid - o] : 0;
        __syncthreads();
        if (tid < BNODES) lexcl[tid] += add;
        __syncthreads();
    }
    if (tid < BNODES) {
        int ex = bstart + lexcl[tid] - lcnt[tid];
        lcur[tid] = ex;
        if (tid < nn) {
            g_cnt[node0 + tid] = lcnt[tid];
            g_offs[node0 + tid] = ex;
            g_dinv[node0 + tid] = rsqrtf((float)lcnt[tid] + 1.0f);
        }
    }
    __syncthreads();
    for (int i = bstart + tid; i < bend; i += 512) {
        unsigned int p = pairs[i];
        int dl = (int)(p >> 24);
        int pos = atomicAdd(&lcur[dl], 1);
        csr[pos] = p & 0xFFFFFFu;
    }
}

// tier B fill (uses N-scan offs)
__global__ __launch_bounds__(256) void k_fill_local(const unsigned int* __restrict__ pairs,
                                                    const int* __restrict__ offs,
                                                    unsigned int* __restrict__ csr,
                                                    int N, int E) {
    __shared__ int lcur[BNODES];
    int b = blockIdx.x;
    int node0 = b << BSH;
    int nn = min(BNODES, N - node0);
    int tid = threadIdx.x;
    for (int i = tid; i < nn; i += 256) lcur[i] = offs[node0 + i];
    __syncthreads();
    int start = offs[node0];
    int end = (node0 + BNODES >= N) ? E : offs[node0 + BNODES];
    for (int i = start + tid; i < end; i += 256) {
        unsigned int p = pairs[i];
        int dl = (int)(p >> 24);
        int pos = atomicAdd(&lcur[dl], 1);
        csr[pos] = p & 0xFFFFFFu;
    }
}

// ======================= aggregation (bf16 in, bf16 out): one wave per node =======================
__global__ __launch_bounds__(256) void k_aggregate_bf2(const unsigned int* __restrict__ xbf,
                                                       const float* __restrict__ dinv,
                                                       const int* __restrict__ offs,
                                                       const int* __restrict__ cnt,
                                                       const unsigned int* __restrict__ csr,
                                                       unsigned int* __restrict__ aggbf,
                                                       int N) {
    int wid = (blockIdx.x * blockDim.x + threadIdx.x) >> 6;
    int lane = threadIdx.x & 63;
    if (wid >= N) return;
    int n = __builtin_amdgcn_readfirstlane(wid);

    float di = dinv[n];
    int start = offs[n];
    int m = cnt[n];

    unsigned int wself = xbf[(size_t)n * 64 + lane];
    float sl = di * di;
    float2 acc = make_float2(sl * __uint_as_float(wself << 16),
                             sl * __uint_as_float(wself & 0xFFFF0000u));

    int i = 0;
    for (; i + 8 <= m; i += 8) {
        int s[8]; float nr[8]; unsigned int w[8];
#pragma unroll
        for (int u = 0; u < 8; ++u) s[u] = (int)csr[start + i + u];
#pragma unroll
        for (int u = 0; u < 8; ++u) w[u] = xbf[(size_t)s[u] * 64 + lane];
#pragma unroll
        for (int u = 0; u < 8; ++u) nr[u] = dinv[s[u]] * di;
#pragma unroll
        for (int u = 0; u < 8; ++u) {
            acc.x += nr[u] * __uint_as_float(w[u] << 16);
            acc.y += nr[u] * __uint_as_float(w[u] & 0xFFFF0000u);
        }
    }
    for (; i < m; ++i) {
        int s0 = (int)csr[start + i];
        float n0 = dinv[s0] * di;
        unsigned int w0 = xbf[(size_t)s0 * 64 + lane];
        acc.x += n0 * __uint_as_float(w0 << 16);
        acc.y += n0 * __uint_as_float(w0 & 0xFFFF0000u);
    }
    aggbf[(size_t)n * 64 + lane] = f2bf(acc.x) | (f2bf(acc.y) << 16);
}

// ======================= MFMA GEMM (bf16 A): out = aggbf @ Wt^T + b =======================
__global__ __launch_bounds__(256) void k_gemm_mfma2(const unsigned short* __restrict__ abf,
                                                    const unsigned short* __restrict__ wt,
                                                    const float* __restrict__ bias,
                                                    float* __restrict__ out, int N) {
    int tid = threadIdx.x;
    int wave = tid >> 6, l = tid & 63;
    int lm = l & 15, lg = l >> 4;
    int rowA = blockIdx.x * 128 + wave * 32;

    f32x4 acc[2][8];
#pragma unroll
    for (int mt = 0; mt < 2; ++mt)
#pragma unroll
        for (int nt = 0; nt < 8; ++nt)
            acc[mt][nt] = (f32x4){0.f, 0.f, 0.f, 0.f};

#pragma unroll
    for (int kk = 0; kk < 4; ++kk) {
        int k = kk * 32 + lg * 8;
        bf16x8 afr[2];
#pragma unroll
        for (int mt = 0; mt < 2; ++mt) {
            int r = rowA + mt * 16 + lm;
            if (r < N)
                afr[mt] = *(const bf16x8*)(abf + (size_t)r * FEAT + k);
            else
                afr[mt] = (bf16x8){0, 0, 0, 0, 0, 0, 0, 0};
        }
#pragma unroll
        for (int nt = 0; nt < 8; ++nt) {
            int col = nt * 16 + lm;
            bf16x8 bfr = *(const bf16x8*)(wt + (size_t)col * FEAT + k);
            acc[0][nt] = __builtin_amdgcn_mfma_f32_16x16x32_bf16(afr[0], bfr, acc[0][nt], 0, 0, 0);
            acc[1][nt] = __builtin_amdgcn_mfma_f32_16x16x32_bf16(afr[1], bfr, acc[1][nt], 0, 0, 0);
        }
    }

#pragma unroll
    for (int nt = 0; nt < 8; ++nt) {
        int col = nt * 16 + lm;
        float bv = bias[col];
#pragma unroll
        for (int mt = 0; mt < 2; ++mt) {
#pragma unroll
            for (int r = 0; r < 4; ++r) {
                int row = rowA + mt * 16 + lg * 4 + r;
                if (row < N) out[(size_t)row * FEAT + col] = acc[mt][nt][r] + bv;
            }
        }
    }
}

// ======================= tier B/C fallback kernels =======================
__global__ __launch_bounds__(256) void k_aggregate(const float* __restrict__ x,
                                                   const float* __restrict__ dinv,
                                                   const int* __restrict__ offs,
                                                   const int* __restrict__ cnt,
                                                   const unsigned int* __restrict__ csr,
                                                   float* __restrict__ out, int N) {
    int wid = (blockIdx.x * blockDim.x + threadIdx.x) >> 6;
    int lane = threadIdx.x & 63;
    if (wid >= N) return;
    int n = __builtin_amdgcn_readfirstlane(wid);

    float di = dinv[n];
    int start = offs[n];
    int m = cnt[n];

    float2 a = ((const float2*)(x + (size_t)n * FEAT))[lane];
    float sl = di * di;
    float2 acc = make_float2(a.x * sl, a.y * sl);

    int i = 0;
    for (; i + 4 <= m; i += 4) {
        int s0 = (int)csr[start + i];
        int s1 = (int)csr[start + i + 1];
        int s2 = (int)csr[start + i + 2];
        int s3 = (int)csr[start + i + 3];
        float n0 = dinv[s0] * di, n1 = dinv[s1] * di, n2 = dinv[s2] * di, n3 = dinv[s3] * di;
        float2 v0 = ((const float2*)(x + (size_t)s0 * FEAT))[lane];
        float2 v1 = ((const float2*)(x + (size_t)s1 * FEAT))[lane];
        float2 v2 = ((const float2*)(x + (size_t)s2 * FEAT))[lane];
        float2 v3 = ((const float2*)(x + (size_t)s3 * FEAT))[lane];
        acc.x += n0 * v0.x; acc.y += n0 * v0.y;
        acc.x += n1 * v1.x; acc.y += n1 * v1.y;
        acc.x += n2 * v2.x; acc.y += n2 * v2.y;
        acc.x += n3 * v3.x; acc.y += n3 * v3.y;
    }
    for (; i < m; ++i) {
        int s0 = (int)csr[start + i];
        float n0 = dinv[s0] * di;
        float2 v0 = ((const float2*)(x + (size_t)s0 * FEAT))[lane];
        acc.x += n0 * v0.x; acc.y += n0 * v0.y;
    }
    ((float2*)(out + (size_t)n * FEAT))[lane] = acc;
}

__global__ __launch_bounds__(256) void k_gemm_inplace(float* __restrict__ out,
                                                      const float* __restrict__ W,
                                                      const float* __restrict__ b, int N) {
    __shared__ float Wl[FEAT * FEAT];
    int tid = threadIdx.x;
    for (int i = tid; i < FEAT * FEAT / 4; i += 256)
        ((float4*)Wl)[i] = ((const float4*)W)[i];
    __syncthreads();

    int j = tid & 127;
    int half = tid >> 7;
    int row0 = blockIdx.x * 16 + half * 8;
    row0 = __builtin_amdgcn_readfirstlane(row0);

    float bj = b[j];
    float acc[8];
#pragma unroll
    for (int r = 0; r < 8; ++r) acc[r] = bj;

    const float* Y = out + (size_t)row0 * FEAT;
    bool full = (row0 + 8 <= N);
    if (full) {
        for (int f4 = 0; f4 < FEAT; f4 += 4) {
            float w0 = Wl[(f4 + 0) * FEAT + j];
            float w1 = Wl[(f4 + 1) * FEAT + j];
            float w2 = Wl[(f4 + 2) * FEAT + j];
            float w3 = Wl[(f4 + 3) * FEAT + j];
#pragma unroll
            for (int r = 0; r < 8; ++r) {
                float4 y = *(const float4*)&Y[(size_t)r * FEAT + f4];
                acc[r] += w0 * y.x + w1 * y.y + w2 * y.z + w3 * y.w;
            }
        }
    } else {
        for (int f = 0; f < FEAT; ++f) {
            float w = Wl[f * FEAT + j];
            for (int r = 0; r < 8; ++r)
                if (row0 + r < N) acc[r] += w * Y[(size_t)r * FEAT + f];
        }
    }
    __syncthreads();
    if (full) {
#pragma unroll
        for (int r = 0; r < 8; ++r) out[(size_t)(row0 + r) * FEAT + j] = acc[r];
    } else {
        for (int r = 0; r < 8; ++r)
            if (row0 + r < N) out[(size_t)(row0 + r) * FEAT + j] = acc[r];
    }
}

__global__ void k_fill_direct(const int* __restrict__ src, const int* __restrict__ dst,
                              int* __restrict__ cur, unsigned int* __restrict__ csr, int E) {
    int e = blockIdx.x * blockDim.x + threadIdx.x;
    if (e < E) {
        int d = dst[e];
        int p = atomicAdd(&cur[d], 1);
        csr[p] = (unsigned int)src[e];
    }
}
__global__ void k_copy_i32(const int* __restrict__ a, int* __restrict__ b, int n) {
    int i = blockIdx.x * blockDim.x + threadIdx.x;
    if (i < n) b[i] = a[i];
}
__global__ void k_deg_initf(float* __restrict__ deg, int N) {
    int i = blockIdx.x * blockDim.x + threadIdx.x;
    if (i < N) deg[i] = 1.0f;
}
__global__ void k_deg_countf(const int* __restrict__ dst, float* __restrict__ deg, int E) {
    int i = blockIdx.x * blockDim.x + threadIdx.x;
    if (i < E) atomicAdd(&deg[dst[i]], 1.0f);
}
__global__ void k_rsqrtf_(float* __restrict__ deg, int N) {
    int i = blockIdx.x * blockDim.x + threadIdx.x;
    if (i < N) deg[i] = rsqrtf(deg[i]);
}
__global__ void k_selfloop(const float* __restrict__ x, const float* __restrict__ dinv,
                           float* __restrict__ out, int N) {
    int t = blockIdx.x * blockDim.x + threadIdx.x;
    int n = t >> 5, c = t & 31;
    if (n >= N) return;
    float s = dinv[n]; s *= s;
    float4 v = ((const float4*)(x + (size_t)n * FEAT))[c];
    v.x *= s; v.y *= s; v.z *= s; v.w *= s;
    ((float4*)(out + (size_t)n * FEAT))[c] = v;
}
__global__ void k_scatter(const int* __restrict__ src, const int* __restrict__ dst,
                          const float* __restrict__ dinv, const float* __restrict__ x,
                          float* __restrict__ out, int E) {
    long long gid = (long long)blockIdx.x * blockDim.x + threadIdx.x;
    long long e = gid >> 6;
    int lane = threadIdx.x & 63;
    if (e >= E) return;
    int s = src[e], d = dst[e];
    float nrm = dinv[s] * dinv[d];
    const float* xs = x + (size_t)s * FEAT;
    float* od = out + (size_t)d * FEAT;
    atomicAdd(&od[lane],      nrm * xs[lane]);
    atomicAdd(&od[lane + 64], nrm * xs[lane + 64]);
}

// ======================= launch =======================
extern "C" void kernel_launch(void* const* d_in, const int* in_sizes, int n_in,
                              void* d_out, int out_size, void* d_ws, size_t ws_size,
                              hipStream_t stream) {
    const float* x = (const float*)d_in[0];
    const int*   ei = (const int*)d_in[1];
    const float* W = (const float*)d_in[2];
    const float* b = (const float*)d_in[3];
    float* out = (float*)d_out;

    int N = in_sizes[0] / FEAT;
    int E = in_sizes[1] / 2;
    const int* src = ei;
    const int* dst = ei + E;

    const int bs = 256;
    int nTiles = (N + STILE - 1) / STILE;
    int NB = (N + BNODES - 1) >> BSH;
    int binGrid = (E + ATILE - 1) / ATILE;
    int hb = (E + HTILE - 1) / HTILE;

    // ---- Tier A layout (256B-aligned bump allocation) ----
    size_t off = 0;
    auto take = [&](size_t bytes) {
        size_t r = off;
        off = (off + bytes + 255) & ~(size_t)255;
        return r;
    };
    size_t o_dinv  = take(4 * (size_t)N);
    size_t o_cnt   = take(4 * (size_t)N);
    size_t o_offs  = take(4 * (size_t)N);
    size_t o_bcnt  = take(4 * (size_t)NB);     // bCnt and cur adjacent: one memset
    size_t o_cur   = take(4 * (size_t)NB);
    size_t o_boffs = take(4 * (size_t)(NB + 1));
    size_t o_pairs = take(4 * (size_t)E);
    size_t o_csr   = take(4 * (size_t)E);
    size_t o_xbf   = take(4 * (size_t)N * 64);
    size_t o_wbf   = take(2 * (size_t)FEAT * FEAT);
    size_t o_aggbf = take(4 * (size_t)N * 64);
    size_t need_A = off;

    bool okNB = (NB <= MAXNB) && (N <= (1 << 24));
    bool can_A = okNB && (ws_size >= need_A);

    if (can_A) {
        char* base = (char*)d_ws;
        float* dinv = (float*)(base + o_dinv);
        int* cnt  = (int*)(base + o_cnt);
        int* offs = (int*)(base + o_offs);
        int* bCnt = (int*)(base + o_bcnt);
        int* cur  = (int*)(base + o_cur);
        int* bOffs= (int*)(base + o_boffs);
        unsigned int* pairs = (unsigned int*)(base + o_pairs);
        unsigned int* csr   = (unsigned int*)(base + o_csr);
        unsigned int* xbf   = (unsigned int*)(base + o_xbf);
        unsigned short* wbf = (unsigned short*)(base + o_wbf);
        unsigned int* aggbf = (unsigned int*)(base + o_aggbf);

        long long n8 = (long long)N * (FEAT / 8);
        int cb = (int)((n8 + 255) / 256);
        int wb = (FEAT * FEAT + 255) / 256;

        // zero bCnt..cur (adjacent) in one memset
        hipMemsetAsync(bCnt, 0, (o_cur + 4 * (size_t)NB) - o_bcnt, stream);
        k_pre2<<<cb + wb + hb, 256, 0, stream>>>(x, xbf, W, wbf, dst, bCnt,
                                                 n8, E, NB, cb, wb, hb);
        k_bin2<<<binGrid, 256, 0, stream>>>(src, dst, bCnt, cur, bOffs, pairs, E, NB);
        k_fill_local2<<<NB, 512, 0, stream>>>(pairs, bOffs, csr, cnt, offs, dinv, N);

        long long t_ag = (long long)N * 64;
        k_aggregate_bf2<<<(int)((t_ag + bs - 1) / bs), bs, 0, stream>>>(
            xbf, dinv, offs, cnt, csr, aggbf, N);
        k_gemm_mfma2<<<(N + 127) / 128, 256, 0, stream>>>(
            (const unsigned short*)aggbf, wbf, b, out, N);
        return;
    }

    // ---- Tier B/C/D ----
    size_t need_direct = (4 * (size_t)N + nTiles + (size_t)E) * 4;
    size_t need_bin    = (4 * (size_t)N + nTiles + 2 * (size_t)E) * 4;
    size_t need_bf     = need_bin + (size_t)N * 64 * 4 + (size_t)FEAT * FEAT * 2 +
                         (size_t)N * 64 * 4;

    float* dinv = (float*)d_ws;
    int* cnt  = (int*)d_ws + N;
    int* offs = (int*)d_ws + 2 * (size_t)N;
    int* cur  = (int*)d_ws + 3 * (size_t)N;
    int* part = (int*)d_ws + 4 * (size_t)N;
    unsigned int* pairs = (unsigned int*)(part + nTiles);
    unsigned int* csr_bin = pairs + E;
    unsigned int* xbf = csr_bin + E;
    unsigned short* wbf = (unsigned short*)(xbf + (size_t)N * 64);
    unsigned int* aggbf = (unsigned int*)(wbf + (size_t)FEAT * FEAT);
    unsigned int* csr_dir = pairs;

    bool can_bin    = (ws_size >= need_bin) && okNB;
    bool can_bf     = can_bin && (ws_size >= need_bf);
    bool can_direct = (ws_size >= need_direct);

    if (can_bin || can_direct) {
        k_zero_i32<<<(N + bs - 1) / bs, bs, 0, stream>>>(cnt, N);
        k_count<<<(E + bs - 1) / bs, bs, 0, stream>>>(dst, cnt, E);
        k_dinv<<<(N + bs - 1) / bs, bs, 0, stream>>>(cnt, dinv, N);
        k_scan_partial<<<nTiles, 256, 0, stream>>>(cnt, part, N);
        k_scan_top<<<1, 256, 0, stream>>>(part, nTiles);
        k_scan_final<<<nTiles, 256, 0, stream>>>(cnt, part, offs, N);

        unsigned int* csr;
        if (can_bin) {
            csr = csr_bin;
            k_bucket_base<<<(NB + bs - 1) / bs, bs, 0, stream>>>(offs, cur, NB);
            k_bin<<<binGrid, 256, 0, stream>>>(src, dst, cur, pairs, E, NB);
            k_fill_local<<<NB, 256, 0, stream>>>(pairs, offs, csr, N, E);
        } else {
            csr = csr_dir;
            k_copy_i32<<<(N + bs - 1) / bs, bs, 0, stream>>>(offs, cur, N);
            k_fill_direct<<<(E + bs - 1) / bs, bs, 0, stream>>>(src, dst, cur, csr, E);
        }

        long long t_ag = (long long)N * 64;
        if (can_bf) {
            long long n8 = (long long)N * (FEAT / 8);
            k_cvt_bf16<<<(int)((n8 + bs - 1) / bs), bs, 0, stream>>>(x, xbf, n8);
            k_cvt_w<<<(FEAT * FEAT + bs - 1) / bs, bs, 0, stream>>>(W, wbf);
            k_aggregate_bf2<<<(int)((t_ag + bs - 1) / bs), bs, 0, stream>>>(
                xbf, dinv, offs, cnt, csr, aggbf, N);
            k_gemm_mfma2<<<(N + 127) / 128, 256, 0, stream>>>(
                (const unsigned short*)aggbf, wbf, b, out, N);
        } else {
            k_aggregate<<<(int)((t_ag + bs - 1) / bs), bs, 0, stream>>>(
                x, dinv, offs, cnt, csr, out, N);
            k_gemm_inplace<<<(N + 15) / 16, 256, 0, stream>>>(out, W, b, N);
        }
    } else {
        float* deg = (float*)d_ws;
        k_deg_initf<<<(N + bs - 1) / bs, bs, 0, stream>>>(deg, N);
        k_deg_countf<<<(E + bs - 1) / bs, bs, 0, stream>>>(dst, deg, E);
        k_rsqrtf_<<<(N + bs - 1) / bs, bs, 0, stream>>>(deg, N);
        long long t_sl = (long long)N * 32;
        k_selfloop<<<(int)((t_sl + bs - 1) / bs), bs, 0, stream>>>(x, deg, out, N);
        long long t_sc = (long long)E * 64;
        k_scatter<<<(int)((t_sc + bs - 1) / bs), bs, 0, stream>>>(src, dst, deg, x, out, E);
        k_gemm_inplace<<<(N + 15) / 16, 256, 0, stream>>>(out, W, b, N);
    }
}

// Round 12
// 251.764 us; speedup vs baseline: 1.4042x; 1.0242x over previous
//
#include <hip/hip_runtime.h>

#define FEAT 128
#define BSH 8
#define BNODES 256            // nodes per bucket = 1<<BSH
#define ATILE 4096            // edges per binning block
#define HTILE 16384           // edges per hist block (in k_pre3)
#define MAXNB 1024            // bin/fill path requires NB <= 1024
#define STILE 1024

typedef __attribute__((ext_vector_type(8))) short bf16x8;
typedef __attribute__((ext_vector_type(4))) float f32x4;

// ======================= tiny kernels =======================
__global__ void k_zero_i32(int* __restrict__ p, int n) {
    int i = blockIdx.x * blockDim.x + threadIdx.x;
    if (i < n) p[i] = 0;
}

__global__ void k_count(const int* __restrict__ dst, int* __restrict__ cnt, int E) {
    int i = blockIdx.x * blockDim.x + threadIdx.x;
    if (i < E) atomicAdd(&cnt[dst[i]], 1);
}

__global__ void k_dinv(const int* __restrict__ cnt, float* __restrict__ dinv, int N) {
    int i = blockIdx.x * blockDim.x + threadIdx.x;
    if (i < N) dinv[i] = rsqrtf((float)cnt[i] + 1.0f);
}

__global__ void k_bucket_base(const int* __restrict__ offs, int* __restrict__ cur, int NB) {
    int b = blockIdx.x * blockDim.x + threadIdx.x;
    if (b < NB) cur[b] = offs[b << BSH];
}

__device__ inline unsigned int f2bf(float f) {
    unsigned int u = __float_as_uint(f);
    return (u + 0x7FFFu + ((u >> 16) & 1u)) >> 16;   // RNE
}

// ======================= K1 (tier A): {cvt W | bucket-hist -> global atomics} =======================
// bCnt must be zeroed (memsetAsync) before this kernel.
__global__ __launch_bounds__(256) void k_pre3(const float* __restrict__ W,
                                              unsigned short* __restrict__ wt,
                                              const int* __restrict__ dst,
                                              int* __restrict__ bCnt,
                                              int E, int NB, int wb, int hb) {
    int blk = blockIdx.x;
    if (blk < wb) {
        int i = blk * 256 + threadIdx.x;
        if (i >= FEAT * FEAT) return;
        int n = i >> 7, k = i & 127;
        wt[i] = (unsigned short)f2bf(W[k * FEAT + n]);
        return;
    }
    blk -= wb;
    if (blk < hb) {
        __shared__ int h[MAXNB];
        int tid = threadIdx.x;
        for (int i = tid; i < NB; i += 256) h[i] = 0;
        __syncthreads();
        int base = blk * HTILE;
        int end = min(base + HTILE, E);
        for (int e = base + tid; e < end; e += 256)
            atomicAdd(&h[dst[e] >> BSH], 1);
        __syncthreads();
        for (int i = tid; i < NB; i += 256)
            if (h[i]) atomicAdd(&bCnt[i], h[i]);
    }
}

// standalone cvt kernels (tier B)
__global__ void k_cvt_bf16(const float* __restrict__ x, unsigned int* __restrict__ xbf,
                           long long n8) {
    long long i = (long long)blockIdx.x * blockDim.x + threadIdx.x;
    if (i >= n8) return;
    float4 a = ((const float4*)x)[i * 2];
    float4 c = ((const float4*)x)[i * 2 + 1];
    uint4 o;
    o.x = f2bf(a.x) | (f2bf(a.y) << 16);
    o.y = f2bf(a.z) | (f2bf(a.w) << 16);
    o.z = f2bf(c.x) | (f2bf(c.y) << 16);
    o.w = f2bf(c.z) | (f2bf(c.w) << 16);
    ((uint4*)xbf)[i] = o;
}
__global__ void k_cvt_w(const float* __restrict__ W, unsigned short* __restrict__ wt) {
    int i = blockIdx.x * blockDim.x + threadIdx.x;
    if (i >= FEAT * FEAT) return;
    int n = i >> 7, k = i & 127;
    wt[i] = (unsigned short)f2bf(W[k * FEAT + n]);
}

// ======================= K2 (tier A): bin with local bucket-scan =======================
// cur[] must be zeroed. bCnt is the final global bucket histogram.
// Block 0 additionally publishes bOffs (exclusive scan of bCnt) + bOffs[NB]=E.
__global__ __launch_bounds__(256) void k_bin2(const int* __restrict__ src,
                                              const int* __restrict__ dst,
                                              const int* __restrict__ bCnt,
                                              int* __restrict__ cur,
                                              int* __restrict__ bOffs,
                                              unsigned int* __restrict__ pairs,
                                              int E, int NB) {
    __shared__ int hist[MAXNB];
    __shared__ int tbase[MAXNB];
    __shared__ int sc[256];
    __shared__ int sc2[256];
    __shared__ unsigned int stM[ATILE];
    __shared__ unsigned short stB[ATILE];

    int tid = threadIdx.x;
    int tileBase = blockIdx.x * ATILE;
    int tileCnt = min(ATILE, E - tileBase);

    for (int i = tid; i < NB; i += 256) hist[i] = 0;
    __syncthreads();

    unsigned int pk[16]; unsigned short bk[16]; unsigned short rk[16];
#pragma unroll
    for (int k = 0; k < 16; ++k) {
        int e = tileBase + k * 256 + tid;
        if (e < E) {
            int s = src[e], d = dst[e];
            int b = d >> BSH;
            int r = atomicAdd(&hist[b], 1);
            pk[k] = (unsigned int)s | ((unsigned int)(d & (BNODES - 1)) << 24);
            bk[k] = (unsigned short)b;
            rk[k] = (unsigned short)r;
        }
    }
    __syncthreads();

    int per = (NB + 255) / 256;
    int myBase = tid * per;
    int ph = 0, pg = 0;
    for (int i = 0; i < per; ++i) {
        int idx = myBase + i;
        if (idx < NB) { ph += hist[idx]; pg += bCnt[idx]; }
    }
    sc[tid] = ph; sc2[tid] = pg;
    __syncthreads();
    for (int o = 1; o < 256; o <<= 1) {
        int ah = (tid >= o) ? sc[tid - o] : 0;
        int ag = (tid >= o) ? sc2[tid - o] : 0;
        __syncthreads();
        sc[tid] += ah; sc2[tid] += ag;
        __syncthreads();
    }
    int run_h = (tid == 0) ? 0 : sc[tid - 1];
    int run_g = (tid == 0) ? 0 : sc2[tid - 1];
    bool pub = (blockIdx.x == 0);
    for (int i = 0; i < per; ++i) {
        int idx = myBase + i;
        if (idx < NB) {
            int ch = hist[idx];
            hist[idx] = run_h;
            if (pub) bOffs[idx] = run_g;
            if (ch > 0) {
                int g = run_g + atomicAdd(&cur[idx], ch);
                tbase[idx] = g - run_h;
            }
            run_h += ch;
            run_g += bCnt[idx];
        }
    }
    if (pub && tid == 0) bOffs[NB] = E;
    __syncthreads();

#pragma unroll
    for (int k = 0; k < 16; ++k) {
        int e = tileBase + k * 256 + tid;
        if (e < E) {
            int slot = hist[bk[k]] + (int)rk[k];
            stM[slot] = pk[k];
            stB[slot] = bk[k];
        }
    }
    __syncthreads();

    for (int s = tid; s < tileCnt; s += 256) {
        int gpos = tbase[stB[s]] + s;
        pairs[gpos] = stM[s];
    }
}

// ======================= tier B bin =======================
__global__ __launch_bounds__(256) void k_bin(const int* __restrict__ src,
                                             const int* __restrict__ dst,
                                             int* __restrict__ cur,
                                             unsigned int* __restrict__ pairs,
                                             int E, int NB) {
    __shared__ int hist[MAXNB];
    __shared__ int tbase[MAXNB];
    __shared__ int sc[256];
    __shared__ unsigned int stM[ATILE];
    __shared__ unsigned short stB[ATILE];

    int tid = threadIdx.x;
    int tileBase = blockIdx.x * ATILE;
    int tileCnt = min(ATILE, E - tileBase);

    for (int i = tid; i < NB; i += 256) hist[i] = 0;
    __syncthreads();

    unsigned int pk[16]; unsigned short bk[16]; unsigned short rk[16];
#pragma unroll
    for (int k = 0; k < 16; ++k) {
        int e = tileBase + k * 256 + tid;
        if (e < E) {
            int s = src[e], d = dst[e];
            int b = d >> BSH;
            int r = atomicAdd(&hist[b], 1);
            pk[k] = (unsigned int)s | ((unsigned int)(d & (BNODES - 1)) << 24);
            bk[k] = (unsigned short)b;
            rk[k] = (unsigned short)r;
        }
    }
    __syncthreads();

    int per = (NB + 255) / 256;
    int myBase = tid * per;
    int partial = 0;
    for (int i = 0; i < per; ++i) {
        int idx = myBase + i;
        if (idx < NB) partial += hist[idx];
    }
    sc[tid] = partial;
    __syncthreads();
    for (int o = 1; o < 256; o <<= 1) {
        int add = (tid >= o) ? sc[tid - o] : 0;
        __syncthreads();
        sc[tid] += add;
        __syncthreads();
    }
    int run = (tid == 0) ? 0 : sc[tid - 1];
    for (int i = 0; i < per; ++i) {
        int idx = myBase + i;
        if (idx < NB) {
            int c = hist[idx];
            hist[idx] = run;
            if (c > 0) {
                int g = atomicAdd(&cur[idx], c);
                tbase[idx] = g - run;
            }
            run += c;
        }
    }
    __syncthreads();

#pragma unroll
    for (int k = 0; k < 16; ++k) {
        int e = tileBase + k * 256 + tid;
        if (e < E) {
            int slot = hist[bk[k]] + (int)rk[k];
            stM[slot] = pk[k];
            stB[slot] = bk[k];
        }
    }
    __syncthreads();

    for (int s = tid; s < tileCnt; s += 256) {
        int gpos = tbase[stB[s]] + s;
        pairs[gpos] = stM[s];
    }
}

// ======================= N-scan (tier B only) =======================
__global__ void k_scan_partial(const int* __restrict__ cnt, int* __restrict__ part, int N) {
    __shared__ int s[256];
    int base = blockIdx.x * STILE;
    int t = threadIdx.x;
    int sum = 0;
#pragma unroll
    for (int k = 0; k < 4; ++k) {
        int i = base + t * 4 + k;
        if (i < N) sum += cnt[i];
    }
    s[t] = sum; __syncthreads();
    for (int off = 128; off > 0; off >>= 1) {
        if (t < off) s[t] += s[t + off];
        __syncthreads();
    }
    if (t == 0) part[blockIdx.x] = s[0];
}

__global__ void k_scan_top(int* __restrict__ part, int nTiles) {
    __shared__ int s[256];
    int t = threadIdx.x;
    int carry = 0;
    for (int base = 0; base < nTiles; base += 256) {
        int i = base + t;
        int v = (i < nTiles) ? part[i] : 0;
        s[t] = v; __syncthreads();
        for (int o = 1; o < 256; o <<= 1) {
            int add = (t >= o) ? s[t - o] : 0;
            __syncthreads();
            s[t] += add;
            __syncthreads();
        }
        if (i < nTiles) part[i] = (s[t] - v) + carry;
        __syncthreads();
        carry += s[255];
        __syncthreads();
    }
}

__global__ void k_scan_final(const int* __restrict__ cnt, const int* __restrict__ part,
                             int* __restrict__ offs, int N) {
    __shared__ int s[256];
    int base = blockIdx.x * STILE;
    int t = threadIdx.x;
    int v[4]; int sum = 0;
#pragma unroll
    for (int k = 0; k < 4; ++k) {
        int i = base + t * 4 + k;
        v[k] = (i < N) ? cnt[i] : 0;
        sum += v[k];
    }
    s[t] = sum; __syncthreads();
    for (int o = 1; o < 256; o <<= 1) {
        int add = (t >= o) ? s[t - o] : 0;
        __syncthreads();
        s[t] += add;
        __syncthreads();
    }
    int excl = (s[t] - sum) + part[blockIdx.x];
#pragma unroll
    for (int k = 0; k < 4; ++k) {
        int i = base + t * 4 + k;
        if (i < N) offs[i] = excl;
        excl += v[k];
    }
}

// ======================= pass B (tier A): fill + dinv + pre-scaled bf16 cvt =======================
// xsb[n] = bf16(dinv[n] * x[n])  — per-edge dinv[src] multiply folded into the operand.
__global__ __launch_bounds__(512) void k_fill_local3(const unsigned int* __restrict__ pairs,
                                                     const int* __restrict__ bOffs,
                                                     unsigned int* __restrict__ csr,
                                                     int* __restrict__ g_cnt,
                                                     int* __restrict__ g_offs,
                                                     float* __restrict__ g_dinv,
                                                     const float* __restrict__ x,
                                                     unsigned int* __restrict__ xsb,
                                                     int N) {
    __shared__ int lcnt[BNODES];
    __shared__ int lexcl[BNODES];
    __shared__ int lcur[BNODES];
    __shared__ float ldv[BNODES];
    int b = blockIdx.x;
    int node0 = b << BSH;
    int nn = min(BNODES, N - node0);
    int tid = threadIdx.x;           // 0..511; BNODES == 256
    int bstart = bOffs[b], bend = bOffs[b + 1];

    if (tid < BNODES) lcnt[tid] = 0;
    __syncthreads();
    for (int i = bstart + tid; i < bend; i += 512)
        atomicAdd(&lcnt[pairs[i] >> 24], 1);
    __syncthreads();
    if (tid < BNODES) lexcl[tid] = lcnt[tid];
    __syncthreads();
    for (int o = 1; o < BNODES; o <<= 1) {
        int add = (tid < BNODES && tid >= o) ? lexcl[tid - o] : 0;
        __syncthreads();
        if (tid < BNODES) lexcl[tid] += add;
        __syncthreads();
    }
    if (tid < BNODES) {
        int ex = bstart + lexcl[tid] - lcnt[tid];
        lcur[tid] = ex;
        float dv = rsqrtf((float)lcnt[tid] + 1.0f);
        ldv[tid] = dv;
        if (tid < nn) {
            g_cnt[node0 + tid] = lcnt[tid];
            g_offs[node0 + tid] = ex;
            g_dinv[node0 + tid] = dv;
        }
    }
    __syncthreads();
    for (int i = bstart + tid; i < bend; i += 512) {
        unsigned int p = pairs[i];
        int dl = (int)(p >> 24);
        int pos = atomicAdd(&lcur[dl], 1);
        csr[pos] = p & 0xFFFFFFu;
    }
    // convert this bucket's rows: xsb[row] = bf16(dinv[row] * x[row])
    int chunks = nn * 16;                         // 8 floats per chunk
    for (int c = tid; c < chunks; c += 512) {
        int nl = c >> 4;
        int seg = c & 15;
        int row = node0 + nl;
        float dv = ldv[nl];
        const float4* xp = (const float4*)(x + (size_t)row * FEAT + seg * 8);
        float4 a = xp[0];
        float4 d = xp[1];
        uint4 o;
        o.x = f2bf(a.x * dv) | (f2bf(a.y * dv) << 16);
        o.y = f2bf(a.z * dv) | (f2bf(a.w * dv) << 16);
        o.z = f2bf(d.x * dv) | (f2bf(d.y * dv) << 16);
        o.w = f2bf(d.z * dv) | (f2bf(d.w * dv) << 16);
        ((uint4*)(xsb + (size_t)row * 64))[seg >> 1] = (seg & 1)
            ? o : o;   // placeholder to keep indexing clear; replaced below
    }
    // NOTE: the above indexing writes uint4 (8 bf16) at seg granularity:
    // each seg covers 8 floats -> 4 u32 words -> one uint4 at word offset seg*4.
    // (Rewritten correctly below; kept single store path.)
}

// Correct, simple version used instead (defined after to keep diff local):
__global__ __launch_bounds__(512) void k_fill_local3b(const unsigned int* __restrict__ pairs,
                                                      const int* __restrict__ bOffs,
                                                      unsigned int* __restrict__ csr,
                                                      int* __restrict__ g_cnt,
                                                      int* __restrict__ g_offs,
                                                      float* __restrict__ g_dinv,
                                                      const float* __restrict__ x,
                                                      unsigned int* __restrict__ xsb,
                                                      int N) {
    __shared__ int lcnt[BNODES];
    __shared__ int lexcl[BNODES];
    __shared__ int lcur[BNODES];
    __shared__ float ldv[BNODES];
    int b = blockIdx.x;
    int node0 = b << BSH;
    int nn = min(BNODES, N - node0);
    int tid = threadIdx.x;
    int bstart = bOffs[b], bend = bOffs[b + 1];

    if (tid < BNODES) lcnt[tid] = 0;
    __syncthreads();
    for (int i = bstart + tid; i < bend; i += 512)
        atomicAdd(&lcnt[pairs[i] >> 24], 1);
    __syncthreads();
    if (tid < BNODES) lexcl[tid] = lcnt[tid];
    __syncthreads();
    for (int o = 1; o < BNODES; o <<= 1) {
        int add = (tid < BNODES && tid >= o) ? lexcl[tid - o] : 0;
        __syncthreads();
        if (tid < BNODES) lexcl[tid] += add;
        __syncthreads();
    }
    if (tid < BNODES) {
        int ex = bstart + lexcl[tid] - lcnt[tid];
        lcur[tid] = ex;
        float dv = rsqrtf((float)lcnt[tid] + 1.0f);
        ldv[tid] = dv;
        if (tid < nn) {
            g_cnt[node0 + tid] = lcnt[tid];
            g_offs[node0 + tid] = ex;
            g_dinv[node0 + tid] = dv;
        }
    }
    __syncthreads();
    for (int i = bstart + tid; i < bend; i += 512) {
        unsigned int p = pairs[i];
        int dl = (int)(p >> 24);
        int pos = atomicAdd(&lcur[dl], 1);
        csr[pos] = p & 0xFFFFFFu;
    }
    // cvt: chunk = 8 floats = 4 u32 out = one uint4 at word offset (seg*4)/4 = seg
    int chunks = nn * 16;
    for (int c = tid; c < chunks; c += 512) {
        int nl = c >> 4;
        int seg = c & 15;          // 16 segs of 8 floats per row
        int row = node0 + nl;
        float dv = ldv[nl];
        const float4* xp = (const float4*)(x + (size_t)row * FEAT + seg * 8);
        float4 a = xp[0];
        float4 d = xp[1];
        uint4 o;
        o.x = f2bf(a.x * dv) | (f2bf(a.y * dv) << 16);
        o.y = f2bf(a.z * dv) | (f2bf(a.w * dv) << 16);
        o.z = f2bf(d.x * dv) | (f2bf(d.y * dv) << 16);
        o.w = f2bf(d.z * dv) | (f2bf(d.w * dv) << 16);
        ((uint4*)(xsb + (size_t)row * 64 + seg * 4))[0] = o;
    }
}

// tier B fill
__global__ __launch_bounds__(256) void k_fill_local(const unsigned int* __restrict__ pairs,
                                                    const int* __restrict__ offs,
                                                    unsigned int* __restrict__ csr,
                                                    int N, int E) {
    __shared__ int lcur[BNODES];
    int b = blockIdx.x;
    int node0 = b << BSH;
    int nn = min(BNODES, N - node0);
    int tid = threadIdx.x;
    for (int i = tid; i < nn; i += 256) lcur[i] = offs[node0 + i];
    __syncthreads();
    int start = offs[node0];
    int end = (node0 + BNODES >= N) ? E : offs[node0 + BNODES];
    for (int i = start + tid; i < end; i += 256) {
        unsigned int p = pairs[i];
        int dl = (int)(p >> 24);
        int pos = atomicAdd(&lcur[dl], 1);
        csr[pos] = p & 0xFFFFFFu;
    }
}

// ======================= aggregation (pre-scaled bf16): one wave per node =======================
// acc = xsb[n] + sum over nbrs xsb[s];  aggbf[n] = bf16(dinv[n] * acc)
__global__ __launch_bounds__(256) void k_aggregate_bf3(const unsigned int* __restrict__ xsb,
                                                       const float* __restrict__ dinv,
                                                       const int* __restrict__ offs,
                                                       const int* __restrict__ cnt,
                                                       const unsigned int* __restrict__ csr,
                                                       unsigned int* __restrict__ aggbf,
                                                       int N) {
    int wid = (blockIdx.x * blockDim.x + threadIdx.x) >> 6;
    int lane = threadIdx.x & 63;
    if (wid >= N) return;
    int n = __builtin_amdgcn_readfirstlane(wid);

    float di = dinv[n];
    int start = offs[n];
    int m = cnt[n];

    unsigned int wself = xsb[(size_t)n * 64 + lane];
    float2 acc = make_float2(__uint_as_float(wself << 16),
                             __uint_as_float(wself & 0xFFFF0000u));

    int i = 0;
    for (; i + 8 <= m; i += 8) {
        int s[8]; unsigned int w[8];
#pragma unroll
        for (int u = 0; u < 8; ++u) s[u] = (int)csr[start + i + u];
#pragma unroll
        for (int u = 0; u < 8; ++u) w[u] = xsb[(size_t)s[u] * 64 + lane];
#pragma unroll
        for (int u = 0; u < 8; ++u) {
            acc.x += __uint_as_float(w[u] << 16);
            acc.y += __uint_as_float(w[u] & 0xFFFF0000u);
        }
    }
    for (; i < m; ++i) {
        int s0 = (int)csr[start + i];
        unsigned int w0 = xsb[(size_t)s0 * 64 + lane];
        acc.x += __uint_as_float(w0 << 16);
        acc.y += __uint_as_float(w0 & 0xFFFF0000u);
    }
    aggbf[(size_t)n * 64 + lane] = f2bf(di * acc.x) | (f2bf(di * acc.y) << 16);
}

// tier B aggregate (unscaled xbf + per-edge dinv)
__global__ __launch_bounds__(256) void k_aggregate_bf2(const unsigned int* __restrict__ xbf,
                                                       const float* __restrict__ dinv,
                                                       const int* __restrict__ offs,
                                                       const int* __restrict__ cnt,
                                                       const unsigned int* __restrict__ csr,
                                                       unsigned int* __restrict__ aggbf,
                                                       int N) {
    int wid = (blockIdx.x * blockDim.x + threadIdx.x) >> 6;
    int lane = threadIdx.x & 63;
    if (wid >= N) return;
    int n = __builtin_amdgcn_readfirstlane(wid);

    float di = dinv[n];
    int start = offs[n];
    int m = cnt[n];

    unsigned int wself = xbf[(size_t)n * 64 + lane];
    float sl = di * di;
    float2 acc = make_float2(sl * __uint_as_float(wself << 16),
                             sl * __uint_as_float(wself & 0xFFFF0000u));

    int i = 0;
    for (; i + 8 <= m; i += 8) {
        int s[8]; float nr[8]; unsigned int w[8];
#pragma unroll
        for (int u = 0; u < 8; ++u) s[u] = (int)csr[start + i + u];
#pragma unroll
        for (int u = 0; u < 8; ++u) w[u] = xbf[(size_t)s[u] * 64 + lane];
#pragma unroll
        for (int u = 0; u < 8; ++u) nr[u] = dinv[s[u]] * di;
#pragma unroll
        for (int u = 0; u < 8; ++u) {
            acc.x += nr[u] * __uint_as_float(w[u] << 16);
            acc.y += nr[u] * __uint_as_float(w[u] & 0xFFFF0000u);
        }
    }
    for (; i < m; ++i) {
        int s0 = (int)csr[start + i];
        float n0 = dinv[s0] * di;
        unsigned int w0 = xbf[(size_t)s0 * 64 + lane];
        acc.x += n0 * __uint_as_float(w0 << 16);
        acc.y += n0 * __uint_as_float(w0 & 0xFFFF0000u);
    }
    aggbf[(size_t)n * 64 + lane] = f2bf(acc.x) | (f2bf(acc.y) << 16);
}

// ======================= MFMA GEMM (bf16 A): out = aggbf @ Wt^T + b =======================
__global__ __launch_bounds__(256) void k_gemm_mfma2(const unsigned short* __restrict__ abf,
                                                    const unsigned short* __restrict__ wt,
                                                    const float* __restrict__ bias,
                                                    float* __restrict__ out, int N) {
    int tid = threadIdx.x;
    int wave = tid >> 6, l = tid & 63;
    int lm = l & 15, lg = l >> 4;
    int rowA = blockIdx.x * 128 + wave * 32;

    f32x4 acc[2][8];
#pragma unroll
    for (int mt = 0; mt < 2; ++mt)
#pragma unroll
        for (int nt = 0; nt < 8; ++nt)
            acc[mt][nt] = (f32x4){0.f, 0.f, 0.f, 0.f};

#pragma unroll
    for (int kk = 0; kk < 4; ++kk) {
        int k = kk * 32 + lg * 8;
        bf16x8 afr[2];
#pragma unroll
        for (int mt = 0; mt < 2; ++mt) {
            int r = rowA + mt * 16 + lm;
            if (r < N)
                afr[mt] = *(const bf16x8*)(abf + (size_t)r * FEAT + k);
            else
                afr[mt] = (bf16x8){0, 0, 0, 0, 0, 0, 0, 0};
        }
#pragma unroll
        for (int nt = 0; nt < 8; ++nt) {
            int col = nt * 16 + lm;
            bf16x8 bfr = *(const bf16x8*)(wt + (size_t)col * FEAT + k);
            acc[0][nt] = __builtin_amdgcn_mfma_f32_16x16x32_bf16(afr[0], bfr, acc[0][nt], 0, 0, 0);
            acc[1][nt] = __builtin_amdgcn_mfma_f32_16x16x32_bf16(afr[1], bfr, acc[1][nt], 0, 0, 0);
        }
    }

#pragma unroll
    for (int nt = 0; nt < 8; ++nt) {
        int col = nt * 16 + lm;
        float bv = bias[col];
#pragma unroll
        for (int mt = 0; mt < 2; ++mt) {
#pragma unroll
            for (int r = 0; r < 4; ++r) {
                int row = rowA + mt * 16 + lg * 4 + r;
                if (row < N) out[(size_t)row * FEAT + col] = acc[mt][nt][r] + bv;
            }
        }
    }
}

// ======================= tier B/C fallback kernels =======================
__global__ __launch_bounds__(256) void k_aggregate(const float* __restrict__ x,
                                                   const float* __restrict__ dinv,
                                                   const int* __restrict__ offs,
                                                   const int* __restrict__ cnt,
                                                   const unsigned int* __restrict__ csr,
                                                   float* __restrict__ out, int N) {
    int wid = (blockIdx.x * blockDim.x + threadIdx.x) >> 6;
    int lane = threadIdx.x & 63;
    if (wid >= N) return;
    int n = __builtin_amdgcn_readfirstlane(wid);

    float di = dinv[n];
    int start = offs[n];
    int m = cnt[n];

    float2 a = ((const float2*)(x + (size_t)n * FEAT))[lane];
    float sl = di * di;
    float2 acc = make_float2(a.x * sl, a.y * sl);

    int i = 0;
    for (; i + 4 <= m; i += 4) {
        int s0 = (int)csr[start + i];
        int s1 = (int)csr[start + i + 1];
        int s2 = (int)csr[start + i + 2];
        int s3 = (int)csr[start + i + 3];
        float n0 = dinv[s0] * di, n1 = dinv[s1] * di, n2 = dinv[s2] * di, n3 = dinv[s3] * di;
        float2 v0 = ((const float2*)(x + (size_t)s0 * FEAT))[lane];
        float2 v1 = ((const float2*)(x + (size_t)s1 * FEAT))[lane];
        float2 v2 = ((const float2*)(x + (size_t)s2 * FEAT))[lane];
        float2 v3 = ((const float2*)(x + (size_t)s3 * FEAT))[lane];
        acc.x += n0 * v0.x; acc.y += n0 * v0.y;
        acc.x += n1 * v1.x; acc.y += n1 * v1.y;
        acc.x += n2 * v2.x; acc.y += n2 * v2.y;
        acc.x += n3 * v3.x; acc.y += n3 * v3.y;
    }
    for (; i < m; ++i) {
        int s0 = (int)csr[start + i];
        float n0 = dinv[s0] * di;
        float2 v0 = ((const float2*)(x + (size_t)s0 * FEAT))[lane];
        acc.x += n0 * v0.x; acc.y += n0 * v0.y;
    }
    ((float2*)(out + (size_t)n * FEAT))[lane] = acc;
}

__global__ __launch_bounds__(256) void k_gemm_inplace(float* __restrict__ out,
                                                      const float* __restrict__ W,
                                                      const float* __restrict__ b, int N) {
    __shared__ float Wl[FEAT * FEAT];
    int tid = threadIdx.x;
    for (int i = tid; i < FEAT * FEAT / 4; i += 256)
        ((float4*)Wl)[i] = ((const float4*)W)[i];
    __syncthreads();

    int j = tid & 127;
    int half = tid >> 7;
    int row0 = blockIdx.x * 16 + half * 8;
    row0 = __builtin_amdgcn_readfirstlane(row0);

    float bj = b[j];
    float acc[8];
#pragma unroll
    for (int r = 0; r < 8; ++r) acc[r] = bj;

    const float* Y = out + (size_t)row0 * FEAT;
    bool full = (row0 + 8 <= N);
    if (full) {
        for (int f4 = 0; f4 < FEAT; f4 += 4) {
            float w0 = Wl[(f4 + 0) * FEAT + j];
            float w1 = Wl[(f4 + 1) * FEAT + j];
            float w2 = Wl[(f4 + 2) * FEAT + j];
            float w3 = Wl[(f4 + 3) * FEAT + j];
#pragma unroll
            for (int r = 0; r < 8; ++r) {
                float4 y = *(const float4*)&Y[(size_t)r * FEAT + f4];
                acc[r] += w0 * y.x + w1 * y.y + w2 * y.z + w3 * y.w;
            }
        }
    } else {
        for (int f = 0; f < FEAT; ++f) {
            float w = Wl[f * FEAT + j];
            for (int r = 0; r < 8; ++r)
                if (row0 + r < N) acc[r] += w * Y[(size_t)r * FEAT + f];
        }
    }
    __syncthreads();
    if (full) {
#pragma unroll
        for (int r = 0; r < 8; ++r) out[(size_t)(row0 + r) * FEAT + j] = acc[r];
    } else {
        for (int r = 0; r < 8; ++r)
            if (row0 + r < N) out[(size_t)(row0 + r) * FEAT + j] = acc[r];
    }
}

__global__ void k_fill_direct(const int* __restrict__ src, const int* __restrict__ dst,
                              int* __restrict__ cur, unsigned int* __restrict__ csr, int E) {
    int e = blockIdx.x * blockDim.x + threadIdx.x;
    if (e < E) {
        int d = dst[e];
        int p = atomicAdd(&cur[d], 1);
        csr[p] = (unsigned int)src[e];
    }
}
__global__ void k_copy_i32(const int* __restrict__ a, int* __restrict__ b, int n) {
    int i = blockIdx.x * blockDim.x + threadIdx.x;
    if (i < n) b[i] = a[i];
}
__global__ void k_deg_initf(float* __restrict__ deg, int N) {
    int i = blockIdx.x * blockDim.x + threadIdx.x;
    if (i < N) deg[i] = 1.0f;
}
__global__ void k_deg_countf(const int* __restrict__ dst, float* __restrict__ deg, int E) {
    int i = blockIdx.x * blockDim.x + threadIdx.x;
    if (i < E) atomicAdd(&deg[dst[i]], 1.0f);
}
__global__ void k_rsqrtf_(float* __restrict__ deg, int N) {
    int i = blockIdx.x * blockDim.x + threadIdx.x;
    if (i < N) deg[i] = rsqrtf(deg[i]);
}
__global__ void k_selfloop(const float* __restrict__ x, const float* __restrict__ dinv,
                           float* __restrict__ out, int N) {
    int t = blockIdx.x * blockDim.x + threadIdx.x;
    int n = t >> 5, c = t & 31;
    if (n >= N) return;
    float s = dinv[n]; s *= s;
    float4 v = ((const float4*)(x + (size_t)n * FEAT))[c];
    v.x *= s; v.y *= s; v.z *= s; v.w *= s;
    ((float4*)(out + (size_t)n * FEAT))[c] = v;
}
__global__ void k_scatter(const int* __restrict__ src, const int* __restrict__ dst,
                          const float* __restrict__ dinv, const float* __restrict__ x,
                          float* __restrict__ out, int E) {
    long long gid = (long long)blockIdx.x * blockDim.x + threadIdx.x;
    long long e = gid >> 6;
    int lane = threadIdx.x & 63;
    if (e >= E) return;
    int s = src[e], d = dst[e];
    float nrm = dinv[s] * dinv[d];
    const float* xs = x + (size_t)s * FEAT;
    float* od = out + (size_t)d * FEAT;
    atomicAdd(&od[lane],      nrm * xs[lane]);
    atomicAdd(&od[lane + 64], nrm * xs[lane + 64]);
}

// ======================= launch =======================
extern "C" void kernel_launch(void* const* d_in, const int* in_sizes, int n_in,
                              void* d_out, int out_size, void* d_ws, size_t ws_size,
                              hipStream_t stream) {
    const float* x = (const float*)d_in[0];
    const int*   ei = (const int*)d_in[1];
    const float* W = (const float*)d_in[2];
    const float* b = (const float*)d_in[3];
    float* out = (float*)d_out;

    int N = in_sizes[0] / FEAT;
    int E = in_sizes[1] / 2;
    const int* src = ei;
    const int* dst = ei + E;

    const int bs = 256;
    int nTiles = (N + STILE - 1) / STILE;
    int NB = (N + BNODES - 1) >> BSH;
    int binGrid = (E + ATILE - 1) / ATILE;
    int hb = (E + HTILE - 1) / HTILE;

    // ---- Tier A layout (256B-aligned bump allocation) ----
    size_t off = 0;
    auto take = [&](size_t bytes) {
        size_t r = off;
        off = (off + bytes + 255) & ~(size_t)255;
        return r;
    };
    size_t o_dinv  = take(4 * (size_t)N);
    size_t o_cnt   = take(4 * (size_t)N);
    size_t o_offs  = take(4 * (size_t)N);
    size_t o_bcnt  = take(4 * (size_t)NB);     // bCnt and cur adjacent: one memset
    size_t o_cur   = take(4 * (size_t)NB);
    size_t o_boffs = take(4 * (size_t)(NB + 1));
    size_t o_pairs = take(4 * (size_t)E);
    size_t o_csr   = take(4 * (size_t)E);
    size_t o_xsb   = take(4 * (size_t)N * 64);
    size_t o_wbf   = take(2 * (size_t)FEAT * FEAT);
    size_t o_aggbf = take(4 * (size_t)N * 64);
    size_t need_A = off;

    bool okNB = (NB <= MAXNB) && (N <= (1 << 24));
    bool can_A = okNB && (ws_size >= need_A);

    if (can_A) {
        char* base = (char*)d_ws;
        float* dinv = (float*)(base + o_dinv);
        int* cnt  = (int*)(base + o_cnt);
        int* offs = (int*)(base + o_offs);
        int* bCnt = (int*)(base + o_bcnt);
        int* cur  = (int*)(base + o_cur);
        int* bOffs= (int*)(base + o_boffs);
        unsigned int* pairs = (unsigned int*)(base + o_pairs);
        unsigned int* csr   = (unsigned int*)(base + o_csr);
        unsigned int* xsb   = (unsigned int*)(base + o_xsb);
        unsigned short* wbf = (unsigned short*)(base + o_wbf);
        unsigned int* aggbf = (unsigned int*)(base + o_aggbf);

        int wb = (FEAT * FEAT + 255) / 256;

        hipMemsetAsync(bCnt, 0, (o_cur + 4 * (size_t)NB) - o_bcnt, stream);
        k_pre3<<<wb + hb, 256, 0, stream>>>(W, wbf, dst, bCnt, E, NB, wb, hb);
        k_bin2<<<binGrid, 256, 0, stream>>>(src, dst, bCnt, cur, bOffs, pairs, E, NB);
        k_fill_local3b<<<NB, 512, 0, stream>>>(pairs, bOffs, csr, cnt, offs, dinv,
                                               x, xsb, N);

        long long t_ag = (long long)N * 64;
        k_aggregate_bf3<<<(int)((t_ag + bs - 1) / bs), bs, 0, stream>>>(
            xsb, dinv, offs, cnt, csr, aggbf, N);
        k_gemm_mfma2<<<(N + 127) / 128, 256, 0, stream>>>(
            (const unsigned short*)aggbf, wbf, b, out, N);
        return;
    }

    // ---- Tier B/C/D ----
    size_t need_direct = (4 * (size_t)N + nTiles + (size_t)E) * 4;
    size_t need_bin    = (4 * (size_t)N + nTiles + 2 * (size_t)E) * 4;
    size_t need_bf     = need_bin + (size_t)N * 64 * 4 + (size_t)FEAT * FEAT * 2 +
                         (size_t)N * 64 * 4;

    float* dinv = (float*)d_ws;
    int* cnt  = (int*)d_ws + N;
    int* offs = (int*)d_ws + 2 * (size_t)N;
    int* cur  = (int*)d_ws + 3 * (size_t)N;
    int* part = (int*)d_ws + 4 * (size_t)N;
    unsigned int* pairs = (unsigned int*)(part + nTiles);
    unsigned int* csr_bin = pairs + E;
    unsigned int* xbf = csr_bin + E;
    unsigned short* wbf = (unsigned short*)(xbf + (size_t)N * 64);
    unsigned int* aggbf = (unsigned int*)(wbf + (size_t)FEAT * FEAT);
    unsigned int* csr_dir = pairs;

    bool can_bin    = (ws_size >= need_bin) && okNB;
    bool can_bf     = can_bin && (ws_size >= need_bf);
    bool can_direct = (ws_size >= need_direct);

    if (can_bin || can_direct) {
        k_zero_i32<<<(N + bs - 1) / bs, bs, 0, stream>>>(cnt, N);
        k_count<<<(E + bs - 1) / bs, bs, 0, stream>>>(dst, cnt, E);
        k_dinv<<<(N + bs - 1) / bs, bs, 0, stream>>>(cnt, dinv, N);
        k_scan_partial<<<nTiles, 256, 0, stream>>>(cnt, part, N);
        k_scan_top<<<1, 256, 0, stream>>>(part, nTiles);
        k_scan_final<<<nTiles, 256, 0, stream>>>(cnt, part, offs, N);

        unsigned int* csr;
        if (can_bin) {
            csr = csr_bin;
            k_bucket_base<<<(NB + bs - 1) / bs, bs, 0, stream>>>(offs, cur, NB);
            k_bin<<<binGrid, 256, 0, stream>>>(src, dst, cur, pairs, E, NB);
            k_fill_local<<<NB, 256, 0, stream>>>(pairs, offs, csr, N, E);
        } else {
            csr = csr_dir;
            k_copy_i32<<<(N + bs - 1) / bs, bs, 0, stream>>>(offs, cur, N);
            k_fill_direct<<<(E + bs - 1) / bs, bs, 0, stream>>>(src, dst, cur, csr, E);
        }

        long long t_ag = (long long)N * 64;
        if (can_bf) {
            long long n8 = (long long)N * (FEAT / 8);
            k_cvt_bf16<<<(int)((n8 + bs - 1) / bs), bs, 0, stream>>>(x, xbf, n8);
            k_cvt_w<<<(FEAT * FEAT + bs - 1) / bs, bs, 0, stream>>>(W, wbf);
            k_aggregate_bf2<<<(int)((t_ag + bs - 1) / bs), bs, 0, stream>>>(
                xbf, dinv, offs, cnt, csr, aggbf, N);
            k_gemm_mfma2<<<(N + 127) / 128, 256, 0, stream>>>(
                (const unsigned short*)aggbf, wbf, b, out, N);
        } else {
            k_aggregate<<<(int)((t_ag + bs - 1) / bs), bs, 0, stream>>>(
                x, dinv, offs, cnt, csr, out, N);
            k_gemm_inplace<<<(N + 15) / 16, 256, 0, stream>>>(out, W, b, N);
        }
    } else {
        float* deg = (float*)d_ws;
        k_deg_initf<<<(N + bs - 1) / bs, bs, 0, stream>>>(deg, N);
        k_deg_countf<<<(E + bs - 1) / bs, bs, 0, stream>>>(dst, deg, E);
        k_rsqrtf_<<<(N + bs - 1) / bs, bs, 0, stream>>>(deg, N);
        long long t_sl = (long long)N * 32;
        k_selfloop<<<(int)((t_sl + bs - 1) / bs), bs, 0, stream>>>(x, deg, out, N);
        long long t_sc = (long long)E * 64;
        k_scatter<<<(int)((t_sc + bs - 1) / bs), bs, 0, stream>>>(src, dst, deg, x, out, E);
        k_gemm_inplace<<<(N + 15) / 16, 256, 0, stream>>>(out, W, b, N);
    }
}